// Round 2
// baseline (385.971 us; speedup 1.0000x reference)
//
#include <hip/hip_runtime.h>
#include <hip/hip_bf16.h>
#include <stdint.h>
#include <math.h>

typedef __bf16 bf16x8 __attribute__((ext_vector_type(8)));
typedef float f32x4 __attribute__((ext_vector_type(4)));
using bf16 = __hip_bfloat16;

__device__ inline float bf2f(bf16 x) { return __bfloat162float(x); }
__device__ inline bf16 f2bf(float x) { return __float2bfloat16(x); }

__device__ inline f32x4 mfma16(bf16x8 a, bf16x8 b, f32x4 c) {
  return __builtin_amdgcn_mfma_f32_16x16x32_bf16(a, b, c, 0, 0, 0);
}

// async global->LDS, 16B per lane. LDS dest must be wave-uniform base + lane*16.
__device__ inline void async16(const bf16* g, bf16* l) {
  __builtin_amdgcn_global_load_lds(
      (const __attribute__((address_space(1))) unsigned int*)g,
      (__attribute__((address_space(3))) unsigned int*)l, 16, 0, 0);
}

// fast GPT-2 gelu: tanh(u) = 1 - 2/(exp(2u)+1); exact limits at +-inf
__device__ inline float gelu_new(float x) {
  float u2 = 1.5957691216057308f * (x + 0.044715f * x * x * x);
  float e = __expf(u2);
  float t = 1.0f - 2.0f * __builtin_amdgcn_rcpf(e + 1.0f);
  return 0.5f * x * (1.0f + t);
}

// ---------------- LayerNorm body (used by prep_all and ln_kernel) ----------------
__device__ inline void ln_body(const float* __restrict__ x, const float* __restrict__ w,
                               const float* __restrict__ bb, bf16* __restrict__ out,
                               int row, int t, float* red) {
  size_t base = (size_t)row * 768;
  float v0 = x[base + t];
  float v1 = x[base + t + 256];
  float v2 = x[base + t + 512];
  float s = v0 + v1 + v2;
  float ss = v0 * v0 + v1 * v1 + v2 * v2;
#pragma unroll
  for (int off = 32; off > 0; off >>= 1) {
    s += __shfl_down(s, off, 64);
    ss += __shfl_down(ss, off, 64);
  }
  int wv = t >> 6, ln = t & 63;
  if (ln == 0) { red[wv] = s; red[4 + wv] = ss; }
  __syncthreads();
  s = red[0] + red[1] + red[2] + red[3];
  ss = red[4] + red[5] + red[6] + red[7];
  float mu = s * (1.0f / 768.0f);
  float var = ss * (1.0f / 768.0f) - mu * mu;
  float rinv = rsqrtf(var + 1e-5f);
  out[base + t]       = f2bf((v0 - mu) * rinv * w[t]       + bb[t]);
  out[base + t + 256] = f2bf((v1 - mu) * rinv * w[t + 256] + bb[t + 256]);
  out[base + t + 512] = f2bf((v2 - mu) * rinv * w[t + 512] + bb[t + 512]);
}

__global__ __launch_bounds__(256) void ln_kernel(const float* __restrict__ x,
                                                 const float* __restrict__ w,
                                                 const float* __restrict__ bb,
                                                 bf16* __restrict__ out) {
  __shared__ float red[8];
  ln_body(x, w, bb, out, blockIdx.x, threadIdx.x, red);
}

// ---------------- transpose body: fp32 in[R][C] -> bf16 out[C][R], 32x32 tile ----------------
__device__ inline void transpose_body(const float* __restrict__ in, bf16* __restrict__ out,
                                      int R, int C, int bx, int by, int t,
                                      float (*tile)[33]) {
  int tx = t & 31, ty = t >> 5;
  int r0 = bx * 32, c0 = by * 32;
#pragma unroll
  for (int j = 0; j < 32; j += 8)
    tile[ty + j][tx] = in[(size_t)(r0 + ty + j) * C + c0 + tx];
  __syncthreads();
#pragma unroll
  for (int j = 0; j < 32; j += 8)
    out[(size_t)(c0 + ty + j) * R + r0 + tx] = f2bf(tile[tx][ty + j]);
}

// ---------------- merged prep: LN1 + all weight transposes + bias pack ----------------
__global__ __launch_bounds__(256) void prep_all(
    const float* __restrict__ resid_pre, const float* __restrict__ ln1_w,
    const float* __restrict__ ln1_b, bf16* __restrict__ n1,
    const float* __restrict__ Wq, const float* __restrict__ Wk,
    const float* __restrict__ Wv, bf16* __restrict__ Wqkv_t,
    const float* __restrict__ W_O, bf16* __restrict__ Wo_t,
    const float* __restrict__ W_in, bf16* __restrict__ Win_t,
    const float* __restrict__ W_out, bf16* __restrict__ Wout_t,
    const float* __restrict__ bq, const float* __restrict__ bk,
    const float* __restrict__ bv, float* __restrict__ bias_qkv) {
  __shared__ float tile[32][33];
  const int t = threadIdx.x;
  int bid = blockIdx.x;
  if (bid < 8192) {                      // LN1
    ln_body(resid_pre, ln1_w, ln1_b, n1, bid, t, &tile[0][0]);
    return;
  }
  bid -= 8192;
  if (bid < 1728) {                      // QKV gather: per-head 768x64 -> 64x768
    int z = bid / 48, r = bid - z * 48;
    int which = z / 12, h = z - which * 12;
    const float* W = (which == 0) ? Wq : ((which == 1) ? Wk : Wv);
    transpose_body(W + (size_t)h * 768 * 64,
                   Wqkv_t + (size_t)which * 589824 + (size_t)h * 64 * 768,
                   768, 64, r % 24, r / 24, t, tile);
    return;
  }
  bid -= 1728;
  if (bid < 576) {                       // W_O [768,768] -> [768,768]^T
    transpose_body(W_O, Wo_t, 768, 768, bid % 24, bid / 24, t, tile);
    return;
  }
  bid -= 576;
  if (bid < 2304) {                      // W_in [768,3072] -> [3072,768]
    transpose_body(W_in, Win_t, 768, 3072, bid % 24, bid / 24, t, tile);
    return;
  }
  bid -= 2304;
  if (bid < 2304) {                      // W_out [3072,768] -> [768,3072]
    transpose_body(W_out, Wout_t, 3072, 768, bid % 96, bid / 96, t, tile);
    return;
  }
  bid -= 2304;
  int i = bid * 256 + t;                 // bias pack, 9 blocks
  if (i < 2304)
    bias_qkv[i] = (i < 768) ? bq[i] : ((i < 1536) ? bk[i - 768] : bv[i - 1536]);
}

// ---------------- legacy GEMM (used for the two N=768 ADDF gemms) ----------------
enum { MODE_QKV = 0, MODE_ADDF = 2, MODE_GELU = 3 };

template <int MODE, int MROWS>
__global__ __launch_bounds__(256) void gemm_bt(
    const bf16* __restrict__ A, const bf16* __restrict__ BT,
    const float* __restrict__ bias,
    const float* __restrict__ addend,
    float* __restrict__ out_f32,
    bf16* __restrict__ out_bf16,
    int M, int N, int K) {
  constexpr int MI = MROWS / 32;
  __shared__ __align__(16) bf16 smem[(MROWS + 128) * 64];
  bf16* Alds = smem;
  bf16* Blds = smem + MROWS * 64;
  const int t = threadIdx.x;
  const int wave = t >> 6, lane = t & 63;
  const int lm = lane & 15, quad = lane >> 4;
  const int wm = wave >> 1, wn = wave & 1;
  const int m0 = blockIdx.x * MROWS, n0 = blockIdx.y * 128;

  f32x4 acc[MI][4] = {};

  for (int k0 = 0; k0 < K; k0 += 64) {
#pragma unroll
    for (int i = 0; i < MI; i++) {
      int c = i * 256 + t;
      int r = c >> 3, cs = c & 7;
      async16(A + (size_t)(m0 + r) * K + k0 + ((cs ^ (r & 7)) << 3), &Alds[c * 8]);
    }
#pragma unroll
    for (int i = 0; i < 4; i++) {
      int c = i * 256 + t;
      int r = c >> 3, cs = c & 7;
      async16(BT + (size_t)(n0 + r) * K + k0 + ((cs ^ (r & 7)) << 3), &Blds[c * 8]);
    }
    __syncthreads();
#pragma unroll
    for (int kk = 0; kk < 64; kk += 32) {
      const int cbase = kk >> 3;  // 0 or 4
      bf16x8 af[MI], bfr[4];
#pragma unroll
      for (int mi = 0; mi < MI; mi++)
        af[mi] = *(const bf16x8*)&Alds[(wm * (MROWS / 2) + mi * 16 + lm) * 64 +
                                       (((cbase + quad) ^ (lm & 7)) << 3)];
#pragma unroll
      for (int ni = 0; ni < 4; ni++)
        bfr[ni] = *(const bf16x8*)&Blds[(wn * 64 + ni * 16 + lm) * 64 +
                                        (((cbase + quad) ^ (lm & 7)) << 3)];
#pragma unroll
      for (int mi = 0; mi < MI; mi++)
#pragma unroll
        for (int ni = 0; ni < 4; ni++)
          acc[mi][ni] = mfma16(af[mi], bfr[ni], acc[mi][ni]);
    }
    __syncthreads();
  }

  // ---------------- epilogue: per-wave LDS transpose -> coalesced 16B stores ----------------
  float bv[4];
#pragma unroll
  for (int ni = 0; ni < 4; ni++) bv[ni] = bias[n0 + wn * 64 + ni * 16 + lm];

  float* sc = (float*)smem + wave * 1088;  // 16x67 (row-major) or 64x17 (V-transposed)
  const bool vseg = (MODE == MODE_QKV) && ((n0 + wn * 64) >= 1536);

#pragma unroll
  for (int mi = 0; mi < MI; mi++) {
    __syncthreads();  // WAR: previous reads done before overwriting scratch
#pragma unroll
    for (int ni = 0; ni < 4; ni++)
#pragma unroll
      for (int reg = 0; reg < 4; reg++) {
        float val = acc[mi][ni][reg] + bv[ni];
        if (vseg) sc[(ni * 16 + lm) * 17 + quad * 4 + reg] = val;
        else      sc[(quad * 4 + reg) * 67 + ni * 16 + lm] = val;
      }
    __syncthreads();  // RAW: scratch writes visible before cross-lane reads

    if (!vseg) {
#pragma unroll
      for (int p = 0; p < 2; p++) {
        int rl = p * 8 + (lane >> 3);
        int cl = (lane & 7) * 8;
        float v[8];
#pragma unroll
        for (int j = 0; j < 8; j++) v[j] = sc[rl * 67 + cl + j];
        int rm = m0 + wm * (MROWS / 2) + mi * 16 + rl;
        int cn0 = n0 + wn * 64 + cl;
        if constexpr (MODE == MODE_GELU) {
          bf16x8 o;
#pragma unroll
          for (int j = 0; j < 8; j++) o[j] = (__bf16)gelu_new(v[j]);
          *(bf16x8*)(out_bf16 + (size_t)rm * N + cn0) = o;
        } else if constexpr (MODE == MODE_ADDF) {
          size_t idx = (size_t)rm * N + cn0;
          f32x4 a0 = *(const f32x4*)(addend + idx);
          f32x4 a1 = *(const f32x4*)(addend + idx + 4);
          f32x4 o0, o1;
#pragma unroll
          for (int j = 0; j < 4; j++) { o0[j] = v[j] + a0[j]; o1[j] = v[4 + j] + a1[j]; }
          *(f32x4*)(out_f32 + idx) = o0;
          *(f32x4*)(out_f32 + idx + 4) = o1;
        } else {  // MODE_QKV, seg 0/1 (Q,K): [b,h,s,e]; Q pre-scaled by 1/sqrt(d)
          int seg = cn0 / 768;
          int lnn = cn0 - seg * 768;
          int h2 = lnn >> 6, e0 = lnn & 63;
          int b2 = rm >> 10, sq = rm & 1023;
          float scale = (seg == 0) ? 0.125f : 1.0f;
          bf16x8 o;
#pragma unroll
          for (int j = 0; j < 8; j++) o[j] = (__bf16)(v[j] * scale);
          *(bf16x8*)(out_bf16 + (size_t)seg * 6291456 +
                     (((size_t)(b2 * 12 + h2) * 1024 + sq) << 6) + e0) = o;
        }
      }
    } else {
      // V chunk: scratch is [e_local 64][s_local 16]; store [b,h,e,s] runs along s
#pragma unroll
      for (int p = 0; p < 2; p++) {
        float v[8];
#pragma unroll
        for (int j = 0; j < 8; j++) v[j] = sc[lane * 17 + p * 8 + j];
        int e_he = n0 + wn * 64 + lane;
        int lnn = e_he - 1536;
        int h2 = lnn >> 6, e2 = lnn & 63;
        int s0 = m0 + wm * (MROWS / 2) + mi * 16 + p * 8;
        int b2 = s0 >> 10, sq = s0 & 1023;
        bf16x8 o;
#pragma unroll
        for (int j = 0; j < 8; j++) o[j] = (__bf16)v[j];
        *(bf16x8*)(out_bf16 + (size_t)2 * 6291456 +
                   (((size_t)(b2 * 12 + h2) * 64 + e2) << 10) + sq) = o;
      }
    }
  }
}

// ---------------- 256x256 8-phase GEMM (K=768 fixed), QKV + GELU modes ----------------
// 8 waves (2M x 4N). Wave tile 128x64 split as 2 A-halves x 2 B-halves.
// REGISTER-RESIDENT fragments: each half is ds_read ONCE per K-tile (24 b128/wave/tile,
// spread 4/8/8/4 over the 4 phases, consumed >=1 phase later), vs 48 in the round-1 port.
// Staging: p0:A1(t+1)->n, p1:B1(t+1)->n, p2:A0(t+2)->c, p3:B0(t+2)->c.
// vmcnt(4) at TAIL of p1 and p3 (before the end barrier, so all waves drain their
// staging loads before any wave's dependent ds_read in the next phase).
#define READ_A(H, BUF) do {                                                           \
  _Pragma("unroll")                                                                   \
  for (int f_ = 0; f_ < 4; f_++) {                                                    \
    _Pragma("unroll")                                                                 \
    for (int k_ = 0; k_ < 2; k_++)                                                    \
      Af[H][f_][k_] = *(const bf16x8*)&sm[(BUF) * 32768 + (H) * 8192 +                \
                                          (aRow + f_ * 16) * 64 +                     \
                                          (((k_ * 4 + quad) ^ lms) << 3)];            \
  }                                                                                   \
} while (0)

#define READ_B(H, BUF) do {                                                           \
  _Pragma("unroll")                                                                   \
  for (int g_ = 0; g_ < 2; g_++) {                                                    \
    _Pragma("unroll")                                                                 \
    for (int k_ = 0; k_ < 2; k_++)                                                    \
      Bf[H][g_][k_] = *(const bf16x8*)&sm[(BUF) * 32768 + 16384 + (H) * 8192 +        \
                                          (bRow + g_ * 16) * 64 +                     \
                                          (((k_ * 4 + quad) ^ lms) << 3)];            \
  }                                                                                   \
} while (0)

#define DO_MFMA(AH, BH) do {                                                          \
  __builtin_amdgcn_s_setprio(1);                                                      \
  _Pragma("unroll")                                                                   \
  for (int k_ = 0; k_ < 2; k_++) {                                                    \
    _Pragma("unroll")                                                                 \
    for (int f_ = 0; f_ < 4; f_++) {                                                  \
      _Pragma("unroll")                                                               \
      for (int g_ = 0; g_ < 2; g_++)                                                  \
        acc[AH][f_][BH][g_] =                                                         \
            mfma16(Af[AH][f_][k_], Bf[BH][g_][k_], acc[AH][f_][BH][g_]);              \
    }                                                                                 \
  }                                                                                   \
  __builtin_amdgcn_s_setprio(0);                                                      \
} while (0)

template <int MODE>
__global__ __launch_bounds__(512, 2) void gemm256(
    const bf16* __restrict__ A, const bf16* __restrict__ BT,
    const float* __restrict__ bias, bf16* __restrict__ out, int N) {
  __shared__ __align__(16) bf16 sm[65536];  // 128 KiB: 2 bufs x (A 2x128x64 | B 2x128x64)
  const int tid = threadIdx.x;
  const int wave = tid >> 6, lane = tid & 63;
  const int lm = lane & 15, quad = lane >> 4, lms = lm & 7;
  const int wm = wave >> 2, wn = wave & 3;

  // XCD-aware bijective swizzle (grid % 8 == 0 for both launches)
  const int cpx = gridDim.x >> 3;
  const int swz = (blockIdx.x & 7) * cpx + (blockIdx.x >> 3);
  const int m0 = (swz & 31) * 256;   // M = 8192 -> 32 row tiles
  const int n0 = (swz >> 5) * 256;

  const int aRow = wm * 64 + lm;     // row within A-half
  const int bRow = wn * 32 + lm;     // row within B-half

  // staging source (pre-swizzled chunks; LDS dest stays linear)
  const int r0 = tid >> 3;
  const int of0 = (((tid & 7) ^ (r0 & 7)) << 3);
  const bf16* sA = A + (size_t)(m0 + r0) * 768 + of0;
  const bf16* sB = BT + (size_t)(n0 + r0) * 768 + of0;

  auto STA = [&](int bb, int ah, int t2) {
    bf16* d = sm + bb * 32768 + ah * 8192 + tid * 8;
    const bf16* s = sA + ah * 98304 + t2 * 64;
    async16(s, d);
    async16(s + 49152, d + 4096);
  };
  auto STB = [&](int bb, int bh, int t2) {
    bf16* d = sm + bb * 32768 + 16384 + bh * 8192 + tid * 8;
    const bf16* s = sB + bh * 98304 + t2 * 64;
    async16(s, d);
    async16(s + 49152, d + 4096);
  };

  f32x4 acc[2][4][2][2] = {};
  bf16x8 Af[2][4][2];   // [A-half][frag row][k-half]
  bf16x8 Bf[2][2][2];   // [B-half][frag col][k-half]

  // prologue: tile0 all 4 halves + tile1 {A0,B0}; drain first 8 loads, then
  // pull tile0's {A0,B0} into registers. Steady-state queue entering p0(0):
  // [A1(0),B1(0),A0(1),B0(1)] = 8 outstanding.
  STA(0, 0, 0); STB(0, 0, 0); STA(0, 1, 0); STB(0, 1, 0);
  STA(1, 0, 1); STB(1, 0, 1);
  asm volatile("s_waitcnt vmcnt(4)" ::: "memory");
  __builtin_amdgcn_s_barrier();
  READ_A(0, 0);
  READ_B(0, 0);

#pragma unroll 2
  for (int tt = 0; tt < 12; ++tt) {
    const int c = tt & 1, nb = c ^ 1;
    // p0: compute (A0,B0); read B1(t); stage A1(t+1)->nb
    READ_B(1, c);
    if (tt + 1 < 12) STA(nb, 1, tt + 1);
    __builtin_amdgcn_s_barrier();
    DO_MFMA(0, 0);
    __builtin_amdgcn_s_barrier();
    // p1: compute (A0,B1); read A1(t); stage B1(t+1)->nb; drain {A0,B0}(t+1)
    READ_A(1, c);
    if (tt + 1 < 12) STB(nb, 1, tt + 1);
    __builtin_amdgcn_s_barrier();
    DO_MFMA(0, 1);
    if (tt + 1 < 12) asm volatile("s_waitcnt vmcnt(4)" ::: "memory");
    __builtin_amdgcn_s_barrier();
    // p2: compute (A1,B0); read A0(t+1) from nb; stage A0(t+2)->c
    if (tt + 1 < 12) READ_A(0, nb);
    if (tt + 2 < 12) STA(c, 0, tt + 2);
    __builtin_amdgcn_s_barrier();
    DO_MFMA(1, 0);
    __builtin_amdgcn_s_barrier();
    // p3: compute (A1,B1); read B0(t+1) from nb; stage B0(t+2)->c; drain {A1,B1}(t+1)
    if (tt + 1 < 12) READ_B(0, nb);
    if (tt + 2 < 12) STB(c, 0, tt + 2);
    __builtin_amdgcn_s_barrier();
    DO_MFMA(1, 1);
    if (tt + 1 < 12) {
      if (tt + 2 < 12) asm volatile("s_waitcnt vmcnt(4)" ::: "memory");
      else             asm volatile("s_waitcnt vmcnt(0)" ::: "memory");
    }
    __builtin_amdgcn_s_barrier();
  }

  // ---------------- epilogue: wave-private LDS transpose, coalesced 16B stores ----------------
  float bvv[2][2];
#pragma unroll
  for (int bh2 = 0; bh2 < 2; bh2++)
#pragma unroll
    for (int g = 0; g < 2; g++)
      bvv[bh2][g] = bias[n0 + bh2 * 128 + wn * 32 + g * 16 + lm];

  float* sc = (float*)sm + wave * 1088;  // 16x68 (row layout) or 64x17 (V layout)

  if constexpr (MODE == MODE_GELU) {
#pragma unroll
    for (int mi = 0; mi < 8; mi++) {
      const int ah = mi >> 2, f = mi & 3;
#pragma unroll
      for (int bh2 = 0; bh2 < 2; bh2++)
#pragma unroll
        for (int g = 0; g < 2; g++)
#pragma unroll
          for (int reg = 0; reg < 4; reg++)
            sc[(quad * 4 + reg) * 68 + bh2 * 32 + g * 16 + lm] =
                acc[ah][f][bh2][g][reg] + bvv[bh2][g];
#pragma unroll
      for (int p = 0; p < 2; p++) {
        int slot = p * 64 + lane;
        int rw = slot >> 3, c8 = (slot & 7) * 8;
        f32x4 u0 = *(const f32x4*)&sc[rw * 68 + c8];
        f32x4 u1 = *(const f32x4*)&sc[rw * 68 + c8 + 4];
        int grow = m0 + ah * 128 + wm * 64 + f * 16 + rw;
        int bh3 = c8 >> 5, cc = c8 & 31;
        int gcol = n0 + bh3 * 128 + wn * 32 + cc;
        bf16x8 o;
#pragma unroll
        for (int j = 0; j < 4; j++) { o[j] = (__bf16)gelu_new(u0[j]); o[4 + j] = (__bf16)gelu_new(u1[j]); }
        *(bf16x8*)(out + (size_t)grow * N + gcol) = o;
      }
    }
  } else {  // MODE_QKV: seg uniform per block (boundaries 768/1536 are 256-aligned)
    const int seg = n0 / 768;
    const float scale = (seg == 0) ? 0.125f : 1.0f;
    if (seg < 2) {
      bf16* qout = out + (size_t)seg * 6291456;
#pragma unroll
      for (int mi = 0; mi < 8; mi++) {
        const int ah = mi >> 2, f = mi & 3;
#pragma unroll
        for (int bh2 = 0; bh2 < 2; bh2++)
#pragma unroll
          for (int g = 0; g < 2; g++)
#pragma unroll
            for (int reg = 0; reg < 4; reg++)
              sc[(quad * 4 + reg) * 68 + bh2 * 32 + g * 16 + lm] =
                  (acc[ah][f][bh2][g][reg] + bvv[bh2][g]) * scale;
#pragma unroll
        for (int p = 0; p < 2; p++) {
          int slot = p * 64 + lane;
          int rw = slot >> 3, c8 = (slot & 7) * 8;
          f32x4 u0 = *(const f32x4*)&sc[rw * 68 + c8];
          f32x4 u1 = *(const f32x4*)&sc[rw * 68 + c8 + 4];
          int grow = m0 + ah * 128 + wm * 64 + f * 16 + rw;
          int bh3 = c8 >> 5, cc = c8 & 31;
          int gcol = n0 + bh3 * 128 + wn * 32 + cc;
          int lnn = gcol - seg * 768;
          int h2 = lnn >> 6, e0 = lnn & 63;
          int b2 = grow >> 10, sq = grow & 1023;
          bf16x8 o;
#pragma unroll
          for (int j = 0; j < 4; j++) { o[j] = (__bf16)u0[j]; o[4 + j] = (__bf16)u1[j]; }
          *(bf16x8*)(qout + (((size_t)(b2 * 12 + h2) * 1024 + sq) << 6) + e0) = o;
        }
      }
    } else {
      // V: transposed scratch [col 64][row 16], store [b,h,e,s] along s
#pragma unroll
      for (int mi = 0; mi < 8; mi++) {
        const int ah = mi >> 2, f = mi & 3;
#pragma unroll
        for (int bh2 = 0; bh2 < 2; bh2++)
#pragma unroll
          for (int g = 0; g < 2; g++)
#pragma unroll
            for (int reg = 0; reg < 4; reg++)
              sc[(bh2 * 32 + g * 16 + lm) * 17 + quad * 4 + reg] =
                  acc[ah][f][bh2][g][reg] + bvv[bh2][g];
#pragma unroll
        for (int p = 0; p < 2; p++) {
          float v[8];
#pragma unroll
          for (int j = 0; j < 8; j++) v[j] = sc[lane * 17 + p * 8 + j];
          int bh3 = lane >> 5, cc = lane & 31;
          int gcol = n0 + bh3 * 128 + wn * 32 + cc;
          int lnn = gcol - 1536;
          int h2 = lnn >> 6, e2 = lnn & 63;
          int s0 = m0 + ah * 128 + wm * 64 + f * 16 + p * 8;
          int b2 = s0 >> 10, sq = s0 & 1023;
          bf16x8 o;
#pragma unroll
          for (int j = 0; j < 8; j++) o[j] = (__bf16)v[j];
          *(bf16x8*)(out + (size_t)2 * 6291456 +
                     (((size_t)(b2 * 12 + h2) * 64 + e2) << 10) + sq) = o;
        }
      }
    }
  }
}

// ---------------- flash attention (swizzled K/V/P tiles; Q pre-scaled) ----------------
__global__ __launch_bounds__(256) void attn_kernel(const bf16* __restrict__ q,
                                                   const bf16* __restrict__ k,
                                                   const bf16* __restrict__ vt,
                                                   bf16* __restrict__ z) {
  const int S = 1024, E = 64;
  __shared__ __align__(16) bf16 Klds[64 * 64];
  __shared__ __align__(16) bf16 Vlds[64 * 64];
  __shared__ __align__(16) bf16 Plds[4 * 16 * 64];
  const int pb = blockIdx.x;   // 0..7
  const int bh = blockIdx.y;   // 0..95
  const int t = threadIdx.x;
  const int wave = t >> 6, lane = t & 63;
  const int lm = lane & 15, quad = lane >> 4;
  const size_t bh_se = (size_t)bh * S * E;
  const int b = bh / 12, h = bh - b * 12;

  for (int seg = 0; seg < 2; seg++) {
    const int qt = seg ? (15 - pb) : pb;
    const int qrow = qt * 64 + wave * 16 + lm;
    bf16x8 qf0 = *(const bf16x8*)(q + bh_se + (size_t)qrow * E + quad * 8);
    bf16x8 qf1 = *(const bf16x8*)(q + bh_se + (size_t)qrow * E + 32 + quad * 8);

    f32x4 acco[4] = {};
    float lsum[4] = {0.f, 0.f, 0.f, 0.f};

    for (int kt = 0; kt <= qt; kt++) {
#pragma unroll
      for (int i = 0; i < 2; i++) {
        int c = i * 256 + t;
        int r = c >> 3, cs = c & 7;
        int sw = (cs ^ (r & 7)) << 3;
        async16(k + bh_se + (size_t)(kt * 64 + r) * E + sw, &Klds[c * 8]);
        async16(vt + bh_se + (size_t)r * S + kt * 64 + sw, &Vlds[c * 8]);
      }
      __syncthreads();

      f32x4 accs[4] = {};
#pragma unroll
      for (int ni = 0; ni < 4; ni++) {
        int row = ni * 16 + lm;
        bf16x8 kf0 = *(const bf16x8*)&Klds[row * 64 + ((quad ^ (lm & 7)) << 3)];
        bf16x8 kf1 = *(const bf16x8*)&Klds[row * 64 + (((4 + quad) ^ (lm & 7)) << 3)];
        accs[ni] = mfma16(qf0, kf0, accs[ni]);
        accs[ni] = mfma16(qf1, kf1, accs[ni]);
      }

      float pv[4][4];
      const int qg = wave * 16 + quad * 4;
      if (kt == qt) {
#pragma unroll
        for (int ni = 0; ni < 4; ni++)
#pragma unroll
          for (int reg = 0; reg < 4; reg++) {
            float e_ = __expf(accs[ni][reg]);
            pv[ni][reg] = ((ni * 16 + lm) > (qg + reg)) ? 0.f : e_;
          }
      } else {
#pragma unroll
        for (int ni = 0; ni < 4; ni++)
#pragma unroll
          for (int reg = 0; reg < 4; reg++)
            pv[ni][reg] = __expf(accs[ni][reg]);
      }

#pragma unroll
      for (int ni = 0; ni < 4; ni++)
#pragma unroll
        for (int reg = 0; reg < 4; reg++) {
          lsum[reg] += pv[ni][reg];
          int pr = quad * 4 + reg;
          int ce = ni * 16 + lm;
          Plds[wave * 1024 + pr * 64 + (((ce >> 3) ^ (pr & 7)) << 3) + (ce & 7)] =
              f2bf(pv[ni][reg]);
        }
      __syncthreads();

      bf16x8 pf0 = *(const bf16x8*)&Plds[wave * 1024 + lm * 64 + ((quad ^ (lm & 7)) << 3)];
      bf16x8 pf1 = *(const bf16x8*)&Plds[wave * 1024 + lm * 64 + (((4 + quad) ^ (lm & 7)) << 3)];
#pragma unroll
      for (int ni = 0; ni < 4; ni++) {
        int row = ni * 16 + lm;
        bf16x8 vf0 = *(const bf16x8*)&Vlds[row * 64 + ((quad ^ (lm & 7)) << 3)];
        bf16x8 vf1 = *(const bf16x8*)&Vlds[row * 64 + (((4 + quad) ^ (lm & 7)) << 3)];
        acco[ni] = mfma16(pf0, vf0, acco[ni]);
        acco[ni] = mfma16(pf1, vf1, acco[ni]);
      }
      __syncthreads();
    }

#pragma unroll
    for (int reg = 0; reg < 4; reg++) {
#pragma unroll
      for (int off = 1; off < 16; off <<= 1) lsum[reg] += __shfl_xor(lsum[reg], off, 16);
    }
    float rl[4];
#pragma unroll
    for (int reg = 0; reg < 4; reg++) rl[reg] = 1.0f / lsum[reg];

#pragma unroll
    for (int ni = 0; ni < 4; ni++)
#pragma unroll
      for (int reg = 0; reg < 4; reg++) {
        int srow = qt * 64 + wave * 16 + quad * 4 + reg;
        size_t idx = (((size_t)(b * 1024 + srow) * 12 + h) << 6) + ni * 16 + lm;
        z[idx] = f2bf(acco[ni][reg] * rl[reg]);
      }
  }
}

// ---------------- launch ----------------
extern "C" void kernel_launch(void* const* d_in, const int* in_sizes, int n_in,
                              void* d_out, int out_size, void* d_ws, size_t ws_size,
                              hipStream_t stream) {
  (void)in_sizes; (void)n_in; (void)out_size; (void)ws_size;
  const float* resid_pre = (const float*)d_in[0];
  const float* ln1_w = (const float*)d_in[1];
  const float* ln1_b = (const float*)d_in[2];
  const float* W_Q = (const float*)d_in[3];
  const float* b_Q = (const float*)d_in[4];
  const float* W_K = (const float*)d_in[5];
  const float* b_K = (const float*)d_in[6];
  const float* W_V = (const float*)d_in[7];
  const float* b_V = (const float*)d_in[8];
  const float* W_O = (const float*)d_in[9];
  const float* b_O = (const float*)d_in[10];
  const float* ln2_w = (const float*)d_in[11];
  const float* ln2_b = (const float*)d_in[12];
  const float* W_in = (const float*)d_in[13];
  const float* b_in = (const float*)d_in[14];
  const float* W_out = (const float*)d_in[15];
  const float* b_out = (const float*)d_in[16];

  char* ws = (char*)d_ws;
  const size_t EB = (size_t)8192 * 768;
  bf16* n1     = (bf16*)(ws);
  bf16* qb     = (bf16*)(ws + EB * 2);   // q, k, vt contiguous (EB elements each)
  bf16* zb     = (bf16*)(ws + EB * 8);
  float* resid = (float*)(ws + EB * 10);
  bf16* act    = (bf16*)(ws + EB * 2);   // reuse q..z region post-attention
  char* wsw = ws + EB * 14;
  bf16* Wqkv_t = (bf16*)(wsw);           // [2304,768]: Wq_t | Wk_t | Wv_t
  bf16* Wo_t   = (bf16*)(wsw + 3 * 1179648);
  bf16* Win_t  = (bf16*)(wsw + 4 * 1179648);
  bf16* Wout_t = (bf16*)(wsw + 4 * 1179648 + 4718592);
  float* bias_qkv = (float*)(wsw + 4 * 1179648 + 4718592 + 9437184);
  bf16* kb  = qb + EB;
  bf16* vtb = qb + 2 * EB;

  // merged: LN1 + QKV gathers + W_O/W_in/W_out transposes + bias pack
  prep_all<<<15113, 256, 0, stream>>>(resid_pre, ln1_w, ln1_b, n1,
                                      W_Q, W_K, W_V, Wqkv_t,
                                      W_O, Wo_t, W_in, Win_t, W_out, Wout_t,
                                      b_Q, b_K, b_V, bias_qkv);

  gemm256<MODE_QKV><<<288, 512, 0, stream>>>(n1, Wqkv_t, bias_qkv, qb, 2304);

  attn_kernel<<<dim3(8, 96), 256, 0, stream>>>(qb, kb, vtb, zb);

  gemm_bt<MODE_ADDF, 64><<<dim3(128, 6), 256, 0, stream>>>(
      zb, Wo_t, b_O, resid_pre, resid, nullptr, 8192, 768, 768);

  ln_kernel<<<8192, 256, 0, stream>>>(resid, ln2_w, ln2_b, n1);

  gemm256<MODE_GELU><<<384, 512, 0, stream>>>(n1, Win_t, b_in, act, 3072);

  gemm_bt<MODE_ADDF, 64><<<dim3(128, 6), 256, 0, stream>>>(
      act, Wout_t, b_out, resid, (float*)d_out, nullptr, 8192, 768, 3072);
}

// Round 3
// 353.023 us; speedup vs baseline: 1.0933x; 1.0933x over previous
//
#include <hip/hip_runtime.h>
#include <hip/hip_bf16.h>
#include <stdint.h>
#include <math.h>

typedef __bf16 bf16x8 __attribute__((ext_vector_type(8)));
typedef float f32x4 __attribute__((ext_vector_type(4)));
using bf16 = __hip_bfloat16;

__device__ inline float bf2f(bf16 x) { return __bfloat162float(x); }
__device__ inline bf16 f2bf(float x) { return __float2bfloat16(x); }

__device__ inline f32x4 mfma16(bf16x8 a, bf16x8 b, f32x4 c) {
  return __builtin_amdgcn_mfma_f32_16x16x32_bf16(a, b, c, 0, 0, 0);
}

// async global->LDS, 16B per lane. LDS dest must be wave-uniform base + lane*16.
__device__ inline void async16(const bf16* g, bf16* l) {
  __builtin_amdgcn_global_load_lds(
      (const __attribute__((address_space(1))) unsigned int*)g,
      (__attribute__((address_space(3))) unsigned int*)l, 16, 0, 0);
}

// fast GPT-2 gelu: tanh(u) = 1 - 2/(exp(2u)+1); exact limits at +-inf
__device__ inline float gelu_new(float x) {
  float u2 = 1.5957691216057308f * (x + 0.044715f * x * x * x);
  float e = __expf(u2);
  float t = 1.0f - 2.0f * __builtin_amdgcn_rcpf(e + 1.0f);
  return 0.5f * x * (1.0f + t);
}

// ---------------- LayerNorm body (used by prep_all and ln_kernel) ----------------
__device__ inline void ln_body(const float* __restrict__ x, const float* __restrict__ w,
                               const float* __restrict__ bb, bf16* __restrict__ out,
                               int row, int t, float* red) {
  size_t base = (size_t)row * 768;
  float v0 = x[base + t];
  float v1 = x[base + t + 256];
  float v2 = x[base + t + 512];
  float s = v0 + v1 + v2;
  float ss = v0 * v0 + v1 * v1 + v2 * v2;
#pragma unroll
  for (int off = 32; off > 0; off >>= 1) {
    s += __shfl_down(s, off, 64);
    ss += __shfl_down(ss, off, 64);
  }
  int wv = t >> 6, ln = t & 63;
  if (ln == 0) { red[wv] = s; red[4 + wv] = ss; }
  __syncthreads();
  s = red[0] + red[1] + red[2] + red[3];
  ss = red[4] + red[5] + red[6] + red[7];
  float mu = s * (1.0f / 768.0f);
  float var = ss * (1.0f / 768.0f) - mu * mu;
  float rinv = rsqrtf(var + 1e-5f);
  out[base + t]       = f2bf((v0 - mu) * rinv * w[t]       + bb[t]);
  out[base + t + 256] = f2bf((v1 - mu) * rinv * w[t + 256] + bb[t + 256]);
  out[base + t + 512] = f2bf((v2 - mu) * rinv * w[t + 512] + bb[t + 512]);
}

__global__ __launch_bounds__(256) void ln_kernel(const float* __restrict__ x,
                                                 const float* __restrict__ w,
                                                 const float* __restrict__ bb,
                                                 bf16* __restrict__ out) {
  __shared__ float red[8];
  ln_body(x, w, bb, out, blockIdx.x, threadIdx.x, red);
}

// ---------------- transpose body: fp32 in[R][C] -> bf16 out[C][R], 32x32 tile ----------------
__device__ inline void transpose_body(const float* __restrict__ in, bf16* __restrict__ out,
                                      int R, int C, int bx, int by, int t,
                                      float (*tile)[33]) {
  int tx = t & 31, ty = t >> 5;
  int r0 = bx * 32, c0 = by * 32;
#pragma unroll
  for (int j = 0; j < 32; j += 8)
    tile[ty + j][tx] = in[(size_t)(r0 + ty + j) * C + c0 + tx];
  __syncthreads();
#pragma unroll
  for (int j = 0; j < 32; j += 8)
    out[(size_t)(c0 + ty + j) * R + r0 + tx] = f2bf(tile[tx][ty + j]);
}

// ---------------- merged prep: LN1 + all weight transposes + bias pack ----------------
__global__ __launch_bounds__(256) void prep_all(
    const float* __restrict__ resid_pre, const float* __restrict__ ln1_w,
    const float* __restrict__ ln1_b, bf16* __restrict__ n1,
    const float* __restrict__ Wq, const float* __restrict__ Wk,
    const float* __restrict__ Wv, bf16* __restrict__ Wqkv_t,
    const float* __restrict__ W_O, bf16* __restrict__ Wo_t,
    const float* __restrict__ W_in, bf16* __restrict__ Win_t,
    const float* __restrict__ W_out, bf16* __restrict__ Wout_t,
    const float* __restrict__ bq, const float* __restrict__ bk,
    const float* __restrict__ bv, float* __restrict__ bias_qkv) {
  __shared__ float tile[32][33];
  const int t = threadIdx.x;
  int bid = blockIdx.x;
  if (bid < 8192) {                      // LN1
    ln_body(resid_pre, ln1_w, ln1_b, n1, bid, t, &tile[0][0]);
    return;
  }
  bid -= 8192;
  if (bid < 1728) {                      // QKV gather: per-head 768x64 -> 64x768
    int z = bid / 48, r = bid - z * 48;
    int which = z / 12, h = z - which * 12;
    const float* W = (which == 0) ? Wq : ((which == 1) ? Wk : Wv);
    transpose_body(W + (size_t)h * 768 * 64,
                   Wqkv_t + (size_t)which * 589824 + (size_t)h * 64 * 768,
                   768, 64, r % 24, r / 24, t, tile);
    return;
  }
  bid -= 1728;
  if (bid < 576) {                       // W_O [768,768] -> [768,768]^T
    transpose_body(W_O, Wo_t, 768, 768, bid % 24, bid / 24, t, tile);
    return;
  }
  bid -= 576;
  if (bid < 2304) {                      // W_in [768,3072] -> [3072,768]
    transpose_body(W_in, Win_t, 768, 3072, bid % 24, bid / 24, t, tile);
    return;
  }
  bid -= 2304;
  if (bid < 2304) {                      // W_out [3072,768] -> [768,3072]
    transpose_body(W_out, Wout_t, 3072, 768, bid % 96, bid / 96, t, tile);
    return;
  }
  bid -= 2304;
  int i = bid * 256 + t;                 // bias pack, 9 blocks
  if (i < 2304)
    bias_qkv[i] = (i < 768) ? bq[i] : ((i < 1536) ? bk[i - 768] : bv[i - 1536]);
}

// ---------------- legacy GEMM (used for the two N=768 ADDF gemms) ----------------
enum { MODE_QKV = 0, MODE_ADDF = 2, MODE_GELU = 3 };

template <int MODE, int MROWS>
__global__ __launch_bounds__(256) void gemm_bt(
    const bf16* __restrict__ A, const bf16* __restrict__ BT,
    const float* __restrict__ bias,
    const float* __restrict__ addend,
    float* __restrict__ out_f32,
    bf16* __restrict__ out_bf16,
    int M, int N, int K) {
  constexpr int MI = MROWS / 32;
  __shared__ __align__(16) bf16 smem[(MROWS + 128) * 64];
  bf16* Alds = smem;
  bf16* Blds = smem + MROWS * 64;
  const int t = threadIdx.x;
  const int wave = t >> 6, lane = t & 63;
  const int lm = lane & 15, quad = lane >> 4;
  const int wm = wave >> 1, wn = wave & 1;
  const int m0 = blockIdx.x * MROWS, n0 = blockIdx.y * 128;

  f32x4 acc[MI][4] = {};

  for (int k0 = 0; k0 < K; k0 += 64) {
#pragma unroll
    for (int i = 0; i < MI; i++) {
      int c = i * 256 + t;
      int r = c >> 3, cs = c & 7;
      async16(A + (size_t)(m0 + r) * K + k0 + ((cs ^ (r & 7)) << 3), &Alds[c * 8]);
    }
#pragma unroll
    for (int i = 0; i < 4; i++) {
      int c = i * 256 + t;
      int r = c >> 3, cs = c & 7;
      async16(BT + (size_t)(n0 + r) * K + k0 + ((cs ^ (r & 7)) << 3), &Blds[c * 8]);
    }
    __syncthreads();
#pragma unroll
    for (int kk = 0; kk < 64; kk += 32) {
      const int cbase = kk >> 3;  // 0 or 4
      bf16x8 af[MI], bfr[4];
#pragma unroll
      for (int mi = 0; mi < MI; mi++)
        af[mi] = *(const bf16x8*)&Alds[(wm * (MROWS / 2) + mi * 16 + lm) * 64 +
                                       (((cbase + quad) ^ (lm & 7)) << 3)];
#pragma unroll
      for (int ni = 0; ni < 4; ni++)
        bfr[ni] = *(const bf16x8*)&Blds[(wn * 64 + ni * 16 + lm) * 64 +
                                        (((cbase + quad) ^ (lm & 7)) << 3)];
#pragma unroll
      for (int mi = 0; mi < MI; mi++)
#pragma unroll
        for (int ni = 0; ni < 4; ni++)
          acc[mi][ni] = mfma16(af[mi], bfr[ni], acc[mi][ni]);
    }
    __syncthreads();
  }

  // ---------------- epilogue: per-wave LDS transpose -> coalesced 16B stores ----------------
  float bv[4];
#pragma unroll
  for (int ni = 0; ni < 4; ni++) bv[ni] = bias[n0 + wn * 64 + ni * 16 + lm];

  float* sc = (float*)smem + wave * 1088;  // 16x67 (row-major) or 64x17 (V-transposed)
  const bool vseg = (MODE == MODE_QKV) && ((n0 + wn * 64) >= 1536);

#pragma unroll
  for (int mi = 0; mi < MI; mi++) {
    __syncthreads();  // WAR: previous reads done before overwriting scratch
#pragma unroll
    for (int ni = 0; ni < 4; ni++)
#pragma unroll
      for (int reg = 0; reg < 4; reg++) {
        float val = acc[mi][ni][reg] + bv[ni];
        if (vseg) sc[(ni * 16 + lm) * 17 + quad * 4 + reg] = val;
        else      sc[(quad * 4 + reg) * 67 + ni * 16 + lm] = val;
      }
    __syncthreads();  // RAW: scratch writes visible before cross-lane reads

    if (!vseg) {
#pragma unroll
      for (int p = 0; p < 2; p++) {
        int rl = p * 8 + (lane >> 3);
        int cl = (lane & 7) * 8;
        float v[8];
#pragma unroll
        for (int j = 0; j < 8; j++) v[j] = sc[rl * 67 + cl + j];
        int rm = m0 + wm * (MROWS / 2) + mi * 16 + rl;
        int cn0 = n0 + wn * 64 + cl;
        if constexpr (MODE == MODE_GELU) {
          bf16x8 o;
#pragma unroll
          for (int j = 0; j < 8; j++) o[j] = (__bf16)gelu_new(v[j]);
          *(bf16x8*)(out_bf16 + (size_t)rm * N + cn0) = o;
        } else if constexpr (MODE == MODE_ADDF) {
          size_t idx = (size_t)rm * N + cn0;
          f32x4 a0 = *(const f32x4*)(addend + idx);
          f32x4 a1 = *(const f32x4*)(addend + idx + 4);
          f32x4 o0, o1;
#pragma unroll
          for (int j = 0; j < 4; j++) { o0[j] = v[j] + a0[j]; o1[j] = v[4 + j] + a1[j]; }
          *(f32x4*)(out_f32 + idx) = o0;
          *(f32x4*)(out_f32 + idx + 4) = o1;
        } else {  // MODE_QKV, seg 0/1 (Q,K): [b,h,s,e]; Q pre-scaled by 1/sqrt(d)
          int seg = cn0 / 768;
          int lnn = cn0 - seg * 768;
          int h2 = lnn >> 6, e0 = lnn & 63;
          int b2 = rm >> 10, sq = rm & 1023;
          float scale = (seg == 0) ? 0.125f : 1.0f;
          bf16x8 o;
#pragma unroll
          for (int j = 0; j < 8; j++) o[j] = (__bf16)(v[j] * scale);
          *(bf16x8*)(out_bf16 + (size_t)seg * 6291456 +
                     (((size_t)(b2 * 12 + h2) * 1024 + sq) << 6) + e0) = o;
        }
      }
    } else {
      // V chunk: scratch is [e_local 64][s_local 16]; store [b,h,e,s] runs along s
#pragma unroll
      for (int p = 0; p < 2; p++) {
        float v[8];
#pragma unroll
        for (int j = 0; j < 8; j++) v[j] = sc[lane * 17 + p * 8 + j];
        int e_he = n0 + wn * 64 + lane;
        int lnn = e_he - 1536;
        int h2 = lnn >> 6, e2 = lnn & 63;
        int s0 = m0 + wm * (MROWS / 2) + mi * 16 + p * 8;
        int b2 = s0 >> 10, sq = s0 & 1023;
        bf16x8 o;
#pragma unroll
        for (int j = 0; j < 8; j++) o[j] = (__bf16)v[j];
        *(bf16x8*)(out_bf16 + (size_t)2 * 6291456 +
                   (((size_t)(b2 * 12 + h2) * 64 + e2) << 10) + sq) = o;
      }
    }
  }
}

// ---------------- 256x256 8-phase GEMM (K=768 fixed), QKV + GELU modes ----------------
// 8 waves (2M x 4N). Wave tile 128x64 split as 2 A-halves x 2 B-halves.
// Quadrant order (A0,B0)->(A0,B1)->(A1,B0)->(A1,B1): operands are ds_read in the
// phase that consumes them (cross-wave overlap + setprio hides the latency; no
// read-ahead register residency -> no spills). Reads/wave/tile: 12/4/12/0 = 28.
// Live operand regs: Af(32) + Bf0(16) + Bf1(16) = 64 VGPR; acc in AGPR.
// Staging: p0:A1(t+1)->nb, p1:B1(t+1)->nb, p2:A0(t+2)->c, p3:B0(t+2)->c.
// Counted vmcnt: p0-tail vmcnt(6) [drains A1(t),B1(t)], p3-tail vmcnt(8)
// [drains A0(t+1),B0(t+1)]; tail tiles degrade 8->4->0. lgkmcnt(0) before each
// phase-end barrier guarantees reads drained before the region is re-staged.
#define READ_A(BUF, H) do {                                                           \
  _Pragma("unroll")                                                                   \
  for (int f_ = 0; f_ < 4; f_++) {                                                    \
    _Pragma("unroll")                                                                 \
    for (int k_ = 0; k_ < 2; k_++)                                                    \
      Af[f_][k_] = *(const bf16x8*)&sm[(BUF) * 32768 + (H) * 8192 +                   \
                                       (aRow + f_ * 16) * 64 +                        \
                                       (((k_ * 4 + quad) ^ lms) << 3)];               \
  }                                                                                   \
} while (0)

#define READ_Bx(BUF, H, DST) do {                                                     \
  _Pragma("unroll")                                                                   \
  for (int g_ = 0; g_ < 2; g_++) {                                                    \
    _Pragma("unroll")                                                                 \
    for (int k_ = 0; k_ < 2; k_++)                                                    \
      DST[g_][k_] = *(const bf16x8*)&sm[(BUF) * 32768 + 16384 + (H) * 8192 +          \
                                        (bRow + g_ * 16) * 64 +                       \
                                        (((k_ * 4 + quad) ^ lms) << 3)];              \
  }                                                                                   \
} while (0)

#define DO_MFMA(AH, BH, BFR) do {                                                     \
  __builtin_amdgcn_s_setprio(1);                                                      \
  _Pragma("unroll")                                                                   \
  for (int k_ = 0; k_ < 2; k_++) {                                                    \
    _Pragma("unroll")                                                                 \
    for (int f_ = 0; f_ < 4; f_++) {                                                  \
      _Pragma("unroll")                                                               \
      for (int g_ = 0; g_ < 2; g_++)                                                  \
        acc[AH][f_][BH][g_] =                                                         \
            mfma16(Af[f_][k_], BFR[g_][k_], acc[AH][f_][BH][g_]);                     \
    }                                                                                 \
  }                                                                                   \
  __builtin_amdgcn_s_setprio(0);                                                      \
} while (0)

template <int MODE>
__global__ __launch_bounds__(512, 2) void gemm256(
    const bf16* __restrict__ A, const bf16* __restrict__ BT,
    const float* __restrict__ bias, bf16* __restrict__ out, int N) {
  __shared__ __align__(16) bf16 sm[65536];  // 128 KiB: 2 bufs x (A 2x128x64 | B 2x128x64)
  const int tid = threadIdx.x;
  const int wave = tid >> 6, lane = tid & 63;
  const int lm = lane & 15, quad = lane >> 4, lms = lm & 7;
  const int wm = wave >> 2, wn = wave & 3;

  // XCD-aware bijective swizzle (grid % 8 == 0 for both launches)
  const int cpx = gridDim.x >> 3;
  const int swz = (blockIdx.x & 7) * cpx + (blockIdx.x >> 3);
  const int m0 = (swz & 31) * 256;   // M = 8192 -> 32 row tiles
  const int n0 = (swz >> 5) * 256;

  const int aRow = wm * 64 + lm;     // row within A-half
  const int bRow = wn * 32 + lm;     // row within B-half

  // staging source (pre-swizzled chunks; LDS dest stays linear)
  const int r0 = tid >> 3;
  const int of0 = (((tid & 7) ^ (r0 & 7)) << 3);
  const bf16* sA = A + (size_t)(m0 + r0) * 768 + of0;
  const bf16* sB = BT + (size_t)(n0 + r0) * 768 + of0;

  auto STA = [&](int bb, int ah, int t2) {
    bf16* d = sm + bb * 32768 + ah * 8192 + tid * 8;
    const bf16* s = sA + ah * 98304 + t2 * 64;
    async16(s, d);
    async16(s + 49152, d + 4096);
  };
  auto STB = [&](int bb, int bh, int t2) {
    bf16* d = sm + bb * 32768 + 16384 + bh * 8192 + tid * 8;
    const bf16* s = sB + bh * 98304 + t2 * 64;
    async16(s, d);
    async16(s + 49152, d + 4096);
  };

  f32x4 acc[2][4][2][2] = {};
  bf16x8 Af[4][2];    // current A-half fragments (overwritten at p2)
  bf16x8 Bf0[2][2];   // B-half 0 fragments (re-read at p2)
  bf16x8 Bf1[2][2];   // B-half 1 fragments (read p1, reused p3)

  // prologue: tile0 all 4 halves + tile1 {A0,B0}; drain tile0's {A0,B0} (8 newest
  // of 12 outstanding allowed through).
  STA(0, 0, 0); STB(0, 0, 0); STA(0, 1, 0); STB(0, 1, 0);
  STA(1, 0, 1); STB(1, 0, 1);
  asm volatile("s_waitcnt vmcnt(8)" ::: "memory");
  __builtin_amdgcn_s_barrier();

#pragma unroll 2
  for (int tt = 0; tt < 12; ++tt) {
    const int c = tt & 1, nb = c ^ 1;
    // p0: compute (A0,B0); read A0,B0; stage A1(t+1)->nb
    READ_A(c, 0);
    READ_Bx(c, 0, Bf0);
    if (tt + 1 < 12) STA(nb, 1, tt + 1);
    __builtin_amdgcn_s_barrier();
    DO_MFMA(0, 0, Bf0);
    asm volatile("s_waitcnt lgkmcnt(0)" ::: "memory");
    if (tt + 1 < 12) asm volatile("s_waitcnt vmcnt(6)" ::: "memory");
    else             asm volatile("s_waitcnt vmcnt(0)" ::: "memory");
    __builtin_amdgcn_s_barrier();
    // p1: compute (A0,B1); read B1; stage B1(t+1)->nb
    READ_Bx(c, 1, Bf1);
    if (tt + 1 < 12) STB(nb, 1, tt + 1);
    __builtin_amdgcn_s_barrier();
    DO_MFMA(0, 1, Bf1);
    asm volatile("s_waitcnt lgkmcnt(0)" ::: "memory");
    __builtin_amdgcn_s_barrier();
    // p2: compute (A1,B0); read A1 + re-read B0; stage A0(t+2)->c (A0 reads done p0)
    READ_A(c, 1);
    READ_Bx(c, 0, Bf0);
    if (tt + 2 < 12) STA(c, 0, tt + 2);
    __builtin_amdgcn_s_barrier();
    DO_MFMA(1, 0, Bf0);
    asm volatile("s_waitcnt lgkmcnt(0)" ::: "memory");
    __builtin_amdgcn_s_barrier();
    // p3: compute (A1,B1); no reads (Af=A1, Bf1 held); stage B0(t+2)->c (B0 reads done p2)
    if (tt + 2 < 12) STB(c, 0, tt + 2);
    __builtin_amdgcn_s_barrier();
    DO_MFMA(1, 1, Bf1);
    if (tt + 2 < 12)      asm volatile("s_waitcnt vmcnt(8)" ::: "memory");
    else if (tt + 1 < 12) asm volatile("s_waitcnt vmcnt(4)" ::: "memory");
    __builtin_amdgcn_s_barrier();
  }

  // ---------------- epilogue: wave-private LDS transpose, coalesced 16B stores ----------------
  float bvv[2][2];
#pragma unroll
  for (int bh2 = 0; bh2 < 2; bh2++)
#pragma unroll
    for (int g = 0; g < 2; g++)
      bvv[bh2][g] = bias[n0 + bh2 * 128 + wn * 32 + g * 16 + lm];

  float* sc = (float*)sm + wave * 1088;  // 16x68 (row layout) or 64x17 (V layout)

  if constexpr (MODE == MODE_GELU) {
#pragma unroll
    for (int mi = 0; mi < 8; mi++) {
      const int ah = mi >> 2, f = mi & 3;
#pragma unroll
      for (int bh2 = 0; bh2 < 2; bh2++)
#pragma unroll
        for (int g = 0; g < 2; g++)
#pragma unroll
          for (int reg = 0; reg < 4; reg++)
            sc[(quad * 4 + reg) * 68 + bh2 * 32 + g * 16 + lm] =
                acc[ah][f][bh2][g][reg] + bvv[bh2][g];
#pragma unroll
      for (int p = 0; p < 2; p++) {
        int slot = p * 64 + lane;
        int rw = slot >> 3, c8 = (slot & 7) * 8;
        f32x4 u0 = *(const f32x4*)&sc[rw * 68 + c8];
        f32x4 u1 = *(const f32x4*)&sc[rw * 68 + c8 + 4];
        int grow = m0 + ah * 128 + wm * 64 + f * 16 + rw;
        int bh3 = c8 >> 5, cc = c8 & 31;
        int gcol = n0 + bh3 * 128 + wn * 32 + cc;
        bf16x8 o;
#pragma unroll
        for (int j = 0; j < 4; j++) { o[j] = (__bf16)gelu_new(u0[j]); o[4 + j] = (__bf16)gelu_new(u1[j]); }
        *(bf16x8*)(out + (size_t)grow * N + gcol) = o;
      }
    }
  } else {  // MODE_QKV: seg uniform per block (boundaries 768/1536 are 256-aligned)
    const int seg = n0 / 768;
    const float scale = (seg == 0) ? 0.125f : 1.0f;
    if (seg < 2) {
      bf16* qout = out + (size_t)seg * 6291456;
#pragma unroll
      for (int mi = 0; mi < 8; mi++) {
        const int ah = mi >> 2, f = mi & 3;
#pragma unroll
        for (int bh2 = 0; bh2 < 2; bh2++)
#pragma unroll
          for (int g = 0; g < 2; g++)
#pragma unroll
            for (int reg = 0; reg < 4; reg++)
              sc[(quad * 4 + reg) * 68 + bh2 * 32 + g * 16 + lm] =
                  (acc[ah][f][bh2][g][reg] + bvv[bh2][g]) * scale;
#pragma unroll
        for (int p = 0; p < 2; p++) {
          int slot = p * 64 + lane;
          int rw = slot >> 3, c8 = (slot & 7) * 8;
          f32x4 u0 = *(const f32x4*)&sc[rw * 68 + c8];
          f32x4 u1 = *(const f32x4*)&sc[rw * 68 + c8 + 4];
          int grow = m0 + ah * 128 + wm * 64 + f * 16 + rw;
          int bh3 = c8 >> 5, cc = c8 & 31;
          int gcol = n0 + bh3 * 128 + wn * 32 + cc;
          int lnn = gcol - seg * 768;
          int h2 = lnn >> 6, e0 = lnn & 63;
          int b2 = grow >> 10, sq = grow & 1023;
          bf16x8 o;
#pragma unroll
          for (int j = 0; j < 4; j++) { o[j] = (__bf16)u0[j]; o[4 + j] = (__bf16)u1[j]; }
          *(bf16x8*)(qout + (((size_t)(b2 * 12 + h2) * 1024 + sq) << 6) + e0) = o;
        }
      }
    } else {
      // V: transposed scratch [col 64][row 16], store [b,h,e,s] along s
#pragma unroll
      for (int mi = 0; mi < 8; mi++) {
        const int ah = mi >> 2, f = mi & 3;
#pragma unroll
        for (int bh2 = 0; bh2 < 2; bh2++)
#pragma unroll
          for (int g = 0; g < 2; g++)
#pragma unroll
            for (int reg = 0; reg < 4; reg++)
              sc[(bh2 * 32 + g * 16 + lm) * 17 + quad * 4 + reg] =
                  acc[ah][f][bh2][g][reg] + bvv[bh2][g];
#pragma unroll
        for (int p = 0; p < 2; p++) {
          float v[8];
#pragma unroll
          for (int j = 0; j < 8; j++) v[j] = sc[lane * 17 + p * 8 + j];
          int bh3 = lane >> 5, cc = lane & 31;
          int gcol = n0 + bh3 * 128 + wn * 32 + cc;
          int lnn = gcol - 1536;
          int h2 = lnn >> 6, e2 = lnn & 63;
          int s0 = m0 + ah * 128 + wm * 64 + f * 16 + p * 8;
          int b2 = s0 >> 10, sq = s0 & 1023;
          bf16x8 o;
#pragma unroll
          for (int j = 0; j < 8; j++) o[j] = (__bf16)v[j];
          *(bf16x8*)(out + (size_t)2 * 6291456 +
                     (((size_t)(b2 * 12 + h2) * 64 + e2) << 10) + sq) = o;
        }
      }
    }
  }
}

// ---------------- flash attention (swizzled K/V/P tiles; Q pre-scaled) ----------------
__global__ __launch_bounds__(256) void attn_kernel(const bf16* __restrict__ q,
                                                   const bf16* __restrict__ k,
                                                   const bf16* __restrict__ vt,
                                                   bf16* __restrict__ z) {
  const int S = 1024, E = 64;
  __shared__ __align__(16) bf16 Klds[64 * 64];
  __shared__ __align__(16) bf16 Vlds[64 * 64];
  __shared__ __align__(16) bf16 Plds[4 * 16 * 64];
  const int pb = blockIdx.x;   // 0..7
  const int bh = blockIdx.y;   // 0..95
  const int t = threadIdx.x;
  const int wave = t >> 6, lane = t & 63;
  const int lm = lane & 15, quad = lane >> 4;
  const size_t bh_se = (size_t)bh * S * E;
  const int b = bh / 12, h = bh - b * 12;

  for (int seg = 0; seg < 2; seg++) {
    const int qt = seg ? (15 - pb) : pb;
    const int qrow = qt * 64 + wave * 16 + lm;
    bf16x8 qf0 = *(const bf16x8*)(q + bh_se + (size_t)qrow * E + quad * 8);
    bf16x8 qf1 = *(const bf16x8*)(q + bh_se + (size_t)qrow * E + 32 + quad * 8);

    f32x4 acco[4] = {};
    float lsum[4] = {0.f, 0.f, 0.f, 0.f};

    for (int kt = 0; kt <= qt; kt++) {
#pragma unroll
      for (int i = 0; i < 2; i++) {
        int c = i * 256 + t;
        int r = c >> 3, cs = c & 7;
        int sw = (cs ^ (r & 7)) << 3;
        async16(k + bh_se + (size_t)(kt * 64 + r) * E + sw, &Klds[c * 8]);
        async16(vt + bh_se + (size_t)r * S + kt * 64 + sw, &Vlds[c * 8]);
      }
      __syncthreads();

      f32x4 accs[4] = {};
#pragma unroll
      for (int ni = 0; ni < 4; ni++) {
        int row = ni * 16 + lm;
        bf16x8 kf0 = *(const bf16x8*)&Klds[row * 64 + ((quad ^ (lm & 7)) << 3)];
        bf16x8 kf1 = *(const bf16x8*)&Klds[row * 64 + (((4 + quad) ^ (lm & 7)) << 3)];
        accs[ni] = mfma16(qf0, kf0, accs[ni]);
        accs[ni] = mfma16(qf1, kf1, accs[ni]);
      }

      float pv[4][4];
      const int qg = wave * 16 + quad * 4;
      if (kt == qt) {
#pragma unroll
        for (int ni = 0; ni < 4; ni++)
#pragma unroll
          for (int reg = 0; reg < 4; reg++) {
            float e_ = __expf(accs[ni][reg]);
            pv[ni][reg] = ((ni * 16 + lm) > (qg + reg)) ? 0.f : e_;
          }
      } else {
#pragma unroll
        for (int ni = 0; ni < 4; ni++)
#pragma unroll
          for (int reg = 0; reg < 4; reg++)
            pv[ni][reg] = __expf(accs[ni][reg]);
      }

#pragma unroll
      for (int ni = 0; ni < 4; ni++)
#pragma unroll
        for (int reg = 0; reg < 4; reg++) {
          lsum[reg] += pv[ni][reg];
          int pr = quad * 4 + reg;
          int ce = ni * 16 + lm;
          Plds[wave * 1024 + pr * 64 + (((ce >> 3) ^ (pr & 7)) << 3) + (ce & 7)] =
              f2bf(pv[ni][reg]);
        }
      __syncthreads();

      bf16x8 pf0 = *(const bf16x8*)&Plds[wave * 1024 + lm * 64 + ((quad ^ (lm & 7)) << 3)];
      bf16x8 pf1 = *(const bf16x8*)&Plds[wave * 1024 + lm * 64 + (((4 + quad) ^ (lm & 7)) << 3)];
#pragma unroll
      for (int ni = 0; ni < 4; ni++) {
        int row = ni * 16 + lm;
        bf16x8 vf0 = *(const bf16x8*)&Vlds[row * 64 + ((quad ^ (lm & 7)) << 3)];
        bf16x8 vf1 = *(const bf16x8*)&Vlds[row * 64 + (((4 + quad) ^ (lm & 7)) << 3)];
        acco[ni] = mfma16(pf0, vf0, acco[ni]);
        acco[ni] = mfma16(pf1, vf1, acco[ni]);
      }
      __syncthreads();
    }

#pragma unroll
    for (int reg = 0; reg < 4; reg++) {
#pragma unroll
      for (int off = 1; off < 16; off <<= 1) lsum[reg] += __shfl_xor(lsum[reg], off, 16);
    }
    float rl[4];
#pragma unroll
    for (int reg = 0; reg < 4; reg++) rl[reg] = 1.0f / lsum[reg];

#pragma unroll
    for (int ni = 0; ni < 4; ni++)
#pragma unroll
      for (int reg = 0; reg < 4; reg++) {
        int srow = qt * 64 + wave * 16 + quad * 4 + reg;
        size_t idx = (((size_t)(b * 1024 + srow) * 12 + h) << 6) + ni * 16 + lm;
        z[idx] = f2bf(acco[ni][reg] * rl[reg]);
      }
  }
}

// ---------------- launch ----------------
extern "C" void kernel_launch(void* const* d_in, const int* in_sizes, int n_in,
                              void* d_out, int out_size, void* d_ws, size_t ws_size,
                              hipStream_t stream) {
  (void)in_sizes; (void)n_in; (void)out_size; (void)ws_size;
  const float* resid_pre = (const float*)d_in[0];
  const float* ln1_w = (const float*)d_in[1];
  const float* ln1_b = (const float*)d_in[2];
  const float* W_Q = (const float*)d_in[3];
  const float* b_Q = (const float*)d_in[4];
  const float* W_K = (const float*)d_in[5];
  const float* b_K = (const float*)d_in[6];
  const float* W_V = (const float*)d_in[7];
  const float* b_V = (const float*)d_in[8];
  const float* W_O = (const float*)d_in[9];
  const float* b_O = (const float*)d_in[10];
  const float* ln2_w = (const float*)d_in[11];
  const float* ln2_b = (const float*)d_in[12];
  const float* W_in = (const float*)d_in[13];
  const float* b_in = (const float*)d_in[14];
  const float* W_out = (const float*)d_in[15];
  const float* b_out = (const float*)d_in[16];

  char* ws = (char*)d_ws;
  const size_t EB = (size_t)8192 * 768;
  bf16* n1     = (bf16*)(ws);
  bf16* qb     = (bf16*)(ws + EB * 2);   // q, k, vt contiguous (EB elements each)
  bf16* zb     = (bf16*)(ws + EB * 8);
  float* resid = (float*)(ws + EB * 10);
  bf16* act    = (bf16*)(ws + EB * 2);   // reuse q..z region post-attention
  char* wsw = ws + EB * 14;
  bf16* Wqkv_t = (bf16*)(wsw);           // [2304,768]: Wq_t | Wk_t | Wv_t
  bf16* Wo_t   = (bf16*)(wsw + 3 * 1179648);
  bf16* Win_t  = (bf16*)(wsw + 4 * 1179648);
  bf16* Wout_t = (bf16*)(wsw + 4 * 1179648 + 4718592);
  float* bias_qkv = (float*)(wsw + 4 * 1179648 + 4718592 + 9437184);
  bf16* kb  = qb + EB;
  bf16* vtb = qb + 2 * EB;

  // merged: LN1 + QKV gathers + W_O/W_in/W_out transposes + bias pack
  prep_all<<<15113, 256, 0, stream>>>(resid_pre, ln1_w, ln1_b, n1,
                                      W_Q, W_K, W_V, Wqkv_t,
                                      W_O, Wo_t, W_in, Win_t, W_out, Wout_t,
                                      b_Q, b_K, b_V, bias_qkv);

  gemm256<MODE_QKV><<<288, 512, 0, stream>>>(n1, Wqkv_t, bias_qkv, qb, 2304);

  attn_kernel<<<dim3(8, 96), 256, 0, stream>>>(qb, kb, vtb, zb);

  gemm_bt<MODE_ADDF, 64><<<dim3(128, 6), 256, 0, stream>>>(
      zb, Wo_t, b_O, resid_pre, resid, nullptr, 8192, 768, 768);

  ln_kernel<<<8192, 256, 0, stream>>>(resid, ln2_w, ln2_b, n1);

  gemm256<MODE_GELU><<<384, 512, 0, stream>>>(n1, Win_t, b_in, act, 3072);

  gemm_bt<MODE_ADDF, 64><<<dim3(128, 6), 256, 0, stream>>>(
      act, Wout_t, b_out, resid, (float*)d_out, nullptr, 8192, 768, 3072);
}

// Round 4
// 345.250 us; speedup vs baseline: 1.1179x; 1.0225x over previous
//
#include <hip/hip_runtime.h>
#include <hip/hip_bf16.h>
#include <stdint.h>
#include <math.h>

typedef __bf16 bf16x8 __attribute__((ext_vector_type(8)));
typedef float f32x4 __attribute__((ext_vector_type(4)));
using bf16 = __hip_bfloat16;

__device__ inline float bf2f(bf16 x) { return __bfloat162float(x); }
__device__ inline bf16 f2bf(float x) { return __float2bfloat16(x); }

__device__ inline f32x4 mfma16(bf16x8 a, bf16x8 b, f32x4 c) {
  return __builtin_amdgcn_mfma_f32_16x16x32_bf16(a, b, c, 0, 0, 0);
}

// async global->LDS, 16B per lane. LDS dest must be wave-uniform base + lane*16.
__device__ inline void async16(const bf16* g, bf16* l) {
  __builtin_amdgcn_global_load_lds(
      (const __attribute__((address_space(1))) unsigned int*)g,
      (__attribute__((address_space(3))) unsigned int*)l, 16, 0, 0);
}

// fast GPT-2 gelu: tanh(u) = 1 - 2/(exp(2u)+1); exact limits at +-inf
__device__ inline float gelu_new(float x) {
  float u2 = 1.5957691216057308f * (x + 0.044715f * x * x * x);
  float e = __expf(u2);
  float t = 1.0f - 2.0f * __builtin_amdgcn_rcpf(e + 1.0f);
  return 0.5f * x * (1.0f + t);
}

// ---------------- LayerNorm body (used by prep_all and ln_kernel) ----------------
__device__ inline void ln_body(const float* __restrict__ x, const float* __restrict__ w,
                               const float* __restrict__ bb, bf16* __restrict__ out,
                               int row, int t, float* red) {
  size_t base = (size_t)row * 768;
  float v0 = x[base + t];
  float v1 = x[base + t + 256];
  float v2 = x[base + t + 512];
  float s = v0 + v1 + v2;
  float ss = v0 * v0 + v1 * v1 + v2 * v2;
#pragma unroll
  for (int off = 32; off > 0; off >>= 1) {
    s += __shfl_down(s, off, 64);
    ss += __shfl_down(ss, off, 64);
  }
  int wv = t >> 6, ln = t & 63;
  if (ln == 0) { red[wv] = s; red[4 + wv] = ss; }
  __syncthreads();
  s = red[0] + red[1] + red[2] + red[3];
  ss = red[4] + red[5] + red[6] + red[7];
  float mu = s * (1.0f / 768.0f);
  float var = ss * (1.0f / 768.0f) - mu * mu;
  float rinv = rsqrtf(var + 1e-5f);
  out[base + t]       = f2bf((v0 - mu) * rinv * w[t]       + bb[t]);
  out[base + t + 256] = f2bf((v1 - mu) * rinv * w[t + 256] + bb[t + 256]);
  out[base + t + 512] = f2bf((v2 - mu) * rinv * w[t + 512] + bb[t + 512]);
}

__global__ __launch_bounds__(256) void ln_kernel(const float* __restrict__ x,
                                                 const float* __restrict__ w,
                                                 const float* __restrict__ bb,
                                                 bf16* __restrict__ out) {
  __shared__ float red[8];
  ln_body(x, w, bb, out, blockIdx.x, threadIdx.x, red);
}

// ---------------- transpose body: fp32 in[R][C] -> bf16 out[C][R], 32x32 tile ----------------
__device__ inline void transpose_body(const float* __restrict__ in, bf16* __restrict__ out,
                                      int R, int C, int bx, int by, int t,
                                      float (*tile)[33]) {
  int tx = t & 31, ty = t >> 5;
  int r0 = bx * 32, c0 = by * 32;
#pragma unroll
  for (int j = 0; j < 32; j += 8)
    tile[ty + j][tx] = in[(size_t)(r0 + ty + j) * C + c0 + tx];
  __syncthreads();
#pragma unroll
  for (int j = 0; j < 32; j += 8)
    out[(size_t)(c0 + ty + j) * R + r0 + tx] = f2bf(tile[tx][ty + j]);
}

// ---------------- merged prep: LN1 + all weight transposes + bias pack ----------------
__global__ __launch_bounds__(256) void prep_all(
    const float* __restrict__ resid_pre, const float* __restrict__ ln1_w,
    const float* __restrict__ ln1_b, bf16* __restrict__ n1,
    const float* __restrict__ Wq, const float* __restrict__ Wk,
    const float* __restrict__ Wv, bf16* __restrict__ Wqkv_t,
    const float* __restrict__ W_O, bf16* __restrict__ Wo_t,
    const float* __restrict__ W_in, bf16* __restrict__ Win_t,
    const float* __restrict__ W_out, bf16* __restrict__ Wout_t,
    const float* __restrict__ bq, const float* __restrict__ bk,
    const float* __restrict__ bv, float* __restrict__ bias_qkv) {
  __shared__ float tile[32][33];
  const int t = threadIdx.x;
  int bid = blockIdx.x;
  if (bid < 8192) {                      // LN1
    ln_body(resid_pre, ln1_w, ln1_b, n1, bid, t, &tile[0][0]);
    return;
  }
  bid -= 8192;
  if (bid < 1728) {                      // QKV gather: per-head 768x64 -> 64x768
    int z = bid / 48, r = bid - z * 48;
    int which = z / 12, h = z - which * 12;
    const float* W = (which == 0) ? Wq : ((which == 1) ? Wk : Wv);
    transpose_body(W + (size_t)h * 768 * 64,
                   Wqkv_t + (size_t)which * 589824 + (size_t)h * 64 * 768,
                   768, 64, r % 24, r / 24, t, tile);
    return;
  }
  bid -= 1728;
  if (bid < 576) {                       // W_O [768,768] -> [768,768]^T
    transpose_body(W_O, Wo_t, 768, 768, bid % 24, bid / 24, t, tile);
    return;
  }
  bid -= 576;
  if (bid < 2304) {                      // W_in [768,3072] -> [3072,768]
    transpose_body(W_in, Win_t, 768, 3072, bid % 24, bid / 24, t, tile);
    return;
  }
  bid -= 2304;
  if (bid < 2304) {                      // W_out [3072,768] -> [768,3072]
    transpose_body(W_out, Wout_t, 3072, 768, bid % 96, bid / 96, t, tile);
    return;
  }
  bid -= 2304;
  int i = bid * 256 + t;                 // bias pack, 9 blocks
  if (i < 2304)
    bias_qkv[i] = (i < 768) ? bq[i] : ((i < 1536) ? bk[i - 768] : bv[i - 1536]);
}

// ---------------- legacy GEMM (used for the two N=768 ADDF gemms) ----------------
enum { MODE_QKV = 0, MODE_ADDF = 2, MODE_GELU = 3 };

template <int MODE, int MROWS>
__global__ __launch_bounds__(256) void gemm_bt(
    const bf16* __restrict__ A, const bf16* __restrict__ BT,
    const float* __restrict__ bias,
    const float* __restrict__ addend,
    float* __restrict__ out_f32,
    bf16* __restrict__ out_bf16,
    int M, int N, int K) {
  constexpr int MI = MROWS / 32;
  __shared__ __align__(16) bf16 smem[(MROWS + 128) * 64];
  bf16* Alds = smem;
  bf16* Blds = smem + MROWS * 64;
  const int t = threadIdx.x;
  const int wave = t >> 6, lane = t & 63;
  const int lm = lane & 15, quad = lane >> 4;
  const int wm = wave >> 1, wn = wave & 1;
  const int m0 = blockIdx.x * MROWS, n0 = blockIdx.y * 128;

  f32x4 acc[MI][4] = {};

  for (int k0 = 0; k0 < K; k0 += 64) {
#pragma unroll
    for (int i = 0; i < MI; i++) {
      int c = i * 256 + t;
      int r = c >> 3, cs = c & 7;
      async16(A + (size_t)(m0 + r) * K + k0 + ((cs ^ (r & 7)) << 3), &Alds[c * 8]);
    }
#pragma unroll
    for (int i = 0; i < 4; i++) {
      int c = i * 256 + t;
      int r = c >> 3, cs = c & 7;
      async16(BT + (size_t)(n0 + r) * K + k0 + ((cs ^ (r & 7)) << 3), &Blds[c * 8]);
    }
    __syncthreads();
#pragma unroll
    for (int kk = 0; kk < 64; kk += 32) {
      const int cbase = kk >> 3;  // 0 or 4
      bf16x8 af[MI], bfr[4];
#pragma unroll
      for (int mi = 0; mi < MI; mi++)
        af[mi] = *(const bf16x8*)&Alds[(wm * (MROWS / 2) + mi * 16 + lm) * 64 +
                                       (((cbase + quad) ^ (lm & 7)) << 3)];
#pragma unroll
      for (int ni = 0; ni < 4; ni++)
        bfr[ni] = *(const bf16x8*)&Blds[(wn * 64 + ni * 16 + lm) * 64 +
                                        (((cbase + quad) ^ (lm & 7)) << 3)];
#pragma unroll
      for (int mi = 0; mi < MI; mi++)
#pragma unroll
        for (int ni = 0; ni < 4; ni++)
          acc[mi][ni] = mfma16(af[mi], bfr[ni], acc[mi][ni]);
    }
    __syncthreads();
  }

  // ---------------- epilogue: per-wave LDS transpose -> coalesced 16B stores ----------------
  float bv[4];
#pragma unroll
  for (int ni = 0; ni < 4; ni++) bv[ni] = bias[n0 + wn * 64 + ni * 16 + lm];

  float* sc = (float*)smem + wave * 1088;  // 16x67 (row-major) or 64x17 (V-transposed)
  const bool vseg = (MODE == MODE_QKV) && ((n0 + wn * 64) >= 1536);

#pragma unroll
  for (int mi = 0; mi < MI; mi++) {
    __syncthreads();  // WAR: previous reads done before overwriting scratch
#pragma unroll
    for (int ni = 0; ni < 4; ni++)
#pragma unroll
      for (int reg = 0; reg < 4; reg++) {
        float val = acc[mi][ni][reg] + bv[ni];
        if (vseg) sc[(ni * 16 + lm) * 17 + quad * 4 + reg] = val;
        else      sc[(quad * 4 + reg) * 67 + ni * 16 + lm] = val;
      }
    __syncthreads();  // RAW: scratch writes visible before cross-lane reads

    if (!vseg) {
#pragma unroll
      for (int p = 0; p < 2; p++) {
        int rl = p * 8 + (lane >> 3);
        int cl = (lane & 7) * 8;
        float v[8];
#pragma unroll
        for (int j = 0; j < 8; j++) v[j] = sc[rl * 67 + cl + j];
        int rm = m0 + wm * (MROWS / 2) + mi * 16 + rl;
        int cn0 = n0 + wn * 64 + cl;
        if constexpr (MODE == MODE_GELU) {
          bf16x8 o;
#pragma unroll
          for (int j = 0; j < 8; j++) o[j] = (__bf16)gelu_new(v[j]);
          *(bf16x8*)(out_bf16 + (size_t)rm * N + cn0) = o;
        } else if constexpr (MODE == MODE_ADDF) {
          size_t idx = (size_t)rm * N + cn0;
          f32x4 a0 = *(const f32x4*)(addend + idx);
          f32x4 a1 = *(const f32x4*)(addend + idx + 4);
          f32x4 o0, o1;
#pragma unroll
          for (int j = 0; j < 4; j++) { o0[j] = v[j] + a0[j]; o1[j] = v[4 + j] + a1[j]; }
          *(f32x4*)(out_f32 + idx) = o0;
          *(f32x4*)(out_f32 + idx + 4) = o1;
        } else {  // MODE_QKV, seg 0/1 (Q,K): [b,h,s,e]; Q pre-scaled by 1/sqrt(d)
          int seg = cn0 / 768;
          int lnn = cn0 - seg * 768;
          int h2 = lnn >> 6, e0 = lnn & 63;
          int b2 = rm >> 10, sq = rm & 1023;
          float scale = (seg == 0) ? 0.125f : 1.0f;
          bf16x8 o;
#pragma unroll
          for (int j = 0; j < 8; j++) o[j] = (__bf16)(v[j] * scale);
          *(bf16x8*)(out_bf16 + (size_t)seg * 6291456 +
                     (((size_t)(b2 * 12 + h2) * 1024 + sq) << 6) + e0) = o;
        }
      }
    } else {
      // V chunk: scratch is [e_local 64][s_local 16]; store [b,h,e,s] runs along s
#pragma unroll
      for (int p = 0; p < 2; p++) {
        float v[8];
#pragma unroll
        for (int j = 0; j < 8; j++) v[j] = sc[lane * 17 + p * 8 + j];
        int e_he = n0 + wn * 64 + lane;
        int lnn = e_he - 1536;
        int h2 = lnn >> 6, e2 = lnn & 63;
        int s0 = m0 + wm * (MROWS / 2) + mi * 16 + p * 8;
        int b2 = s0 >> 10, sq = s0 & 1023;
        bf16x8 o;
#pragma unroll
        for (int j = 0; j < 8; j++) o[j] = (__bf16)v[j];
        *(bf16x8*)(out_bf16 + (size_t)2 * 6291456 +
                   (((size_t)(b2 * 12 + h2) * 64 + e2) << 10) + sq) = o;
      }
    }
  }
}

// ---------------- 256x128 GEMM, 512 threads / 8 waves (4M x 2N), wave-tile 64x64 ----
// Same proven 2-barrier K-loop as gemm_bt; bigger M-tile cuts B-staging traffic 2x
// (B staged M/256 times instead of M/128). acc stays 64 f32/lane -> VGPR ~110,
// __launch_bounds__(512,4) pins the <=128-VGPR tier so 2 blocks/CU stay resident
// (16 waves/CU of TLP to hide staging latency; LDS 48KB allows 3).
template <int MODE>
__global__ __launch_bounds__(512, 4) void gemm_bt512(
    const bf16* __restrict__ A, const bf16* __restrict__ BT,
    const float* __restrict__ bias,
    bf16* __restrict__ out_bf16,
    int M, int N, int K) {
  __shared__ __align__(16) bf16 smem[(256 + 128) * 64];  // 48 KiB
  bf16* Alds = smem;
  bf16* Blds = smem + 256 * 64;
  const int t = threadIdx.x;
  const int wave = t >> 6, lane = t & 63;
  const int lm = lane & 15, quad = lane >> 4;
  const int wm = wave >> 1, wn = wave & 1;   // 4 x 2 wave grid
  const int m0 = blockIdx.x * 256, n0 = blockIdx.y * 128;

  f32x4 acc[4][4] = {};

  for (int k0 = 0; k0 < K; k0 += 64) {
#pragma unroll
    for (int i = 0; i < 4; i++) {            // A: 256 rows x 64 cols = 32KB
      int c = i * 512 + t;
      int r = c >> 3, cs = c & 7;
      async16(A + (size_t)(m0 + r) * K + k0 + ((cs ^ (r & 7)) << 3), &Alds[c * 8]);
    }
#pragma unroll
    for (int i = 0; i < 2; i++) {            // B: 128 rows x 64 cols = 16KB
      int c = i * 512 + t;
      int r = c >> 3, cs = c & 7;
      async16(BT + (size_t)(n0 + r) * K + k0 + ((cs ^ (r & 7)) << 3), &Blds[c * 8]);
    }
    __syncthreads();
#pragma unroll
    for (int kk = 0; kk < 64; kk += 32) {
      const int cbase = kk >> 3;  // 0 or 4
      bf16x8 af[4], bfr[4];
#pragma unroll
      for (int mi = 0; mi < 4; mi++)
        af[mi] = *(const bf16x8*)&Alds[(wm * 64 + mi * 16 + lm) * 64 +
                                       (((cbase + quad) ^ (lm & 7)) << 3)];
#pragma unroll
      for (int ni = 0; ni < 4; ni++)
        bfr[ni] = *(const bf16x8*)&Blds[(wn * 64 + ni * 16 + lm) * 64 +
                                        (((cbase + quad) ^ (lm & 7)) << 3)];
#pragma unroll
      for (int mi = 0; mi < 4; mi++)
#pragma unroll
        for (int ni = 0; ni < 4; ni++)
          acc[mi][ni] = mfma16(af[mi], bfr[ni], acc[mi][ni]);
    }
    __syncthreads();
  }

  // ---------------- epilogue: per-wave LDS transpose -> coalesced 16B stores ----------------
  float bv[4];
#pragma unroll
  for (int ni = 0; ni < 4; ni++) bv[ni] = bias[n0 + wn * 64 + ni * 16 + lm];

  float* sc = (float*)smem + wave * 1088;  // 8 waves x 1088 floats = 34KB <= 48KB
  const bool vseg = (MODE == MODE_QKV) && ((n0 + wn * 64) >= 1536);

#pragma unroll
  for (int mi = 0; mi < 4; mi++) {
    __syncthreads();  // WAR: previous reads done before overwriting scratch
#pragma unroll
    for (int ni = 0; ni < 4; ni++)
#pragma unroll
      for (int reg = 0; reg < 4; reg++) {
        float val = acc[mi][ni][reg] + bv[ni];
        if (vseg) sc[(ni * 16 + lm) * 17 + quad * 4 + reg] = val;
        else      sc[(quad * 4 + reg) * 67 + ni * 16 + lm] = val;
      }
    __syncthreads();  // RAW: scratch writes visible before cross-lane reads

    if (!vseg) {
#pragma unroll
      for (int p = 0; p < 2; p++) {
        int rl = p * 8 + (lane >> 3);
        int cl = (lane & 7) * 8;
        float v[8];
#pragma unroll
        for (int j = 0; j < 8; j++) v[j] = sc[rl * 67 + cl + j];
        int rm = m0 + wm * 64 + mi * 16 + rl;
        int cn0 = n0 + wn * 64 + cl;
        if constexpr (MODE == MODE_GELU) {
          bf16x8 o;
#pragma unroll
          for (int j = 0; j < 8; j++) o[j] = (__bf16)gelu_new(v[j]);
          *(bf16x8*)(out_bf16 + (size_t)rm * N + cn0) = o;
        } else {  // MODE_QKV, seg 0/1 (Q,K): [b,h,s,e]; Q pre-scaled by 1/sqrt(d)
          int seg = cn0 / 768;
          int lnn = cn0 - seg * 768;
          int h2 = lnn >> 6, e0 = lnn & 63;
          int b2 = rm >> 10, sq = rm & 1023;
          float scale = (seg == 0) ? 0.125f : 1.0f;
          bf16x8 o;
#pragma unroll
          for (int j = 0; j < 8; j++) o[j] = (__bf16)(v[j] * scale);
          *(bf16x8*)(out_bf16 + (size_t)seg * 6291456 +
                     (((size_t)(b2 * 12 + h2) * 1024 + sq) << 6) + e0) = o;
        }
      }
    } else {
      // V chunk: scratch is [e_local 64][s_local 16]; store [b,h,e,s] runs along s
#pragma unroll
      for (int p = 0; p < 2; p++) {
        float v[8];
#pragma unroll
        for (int j = 0; j < 8; j++) v[j] = sc[lane * 17 + p * 8 + j];
        int e_he = n0 + wn * 64 + lane;
        int lnn = e_he - 1536;
        int h2 = lnn >> 6, e2 = lnn & 63;
        int s0 = m0 + wm * 64 + mi * 16 + p * 8;
        int b2 = s0 >> 10, sq = s0 & 1023;
        bf16x8 o;
#pragma unroll
        for (int j = 0; j < 8; j++) o[j] = (__bf16)v[j];
        *(bf16x8*)(out_bf16 + (size_t)2 * 6291456 +
                   (((size_t)(b2 * 12 + h2) * 64 + e2) << 10) + sq) = o;
      }
    }
  }
}

// ---------------- flash attention (swizzled K/V/P tiles; Q pre-scaled) ----------------
__global__ __launch_bounds__(256) void attn_kernel(const bf16* __restrict__ q,
                                                   const bf16* __restrict__ k,
                                                   const bf16* __restrict__ vt,
                                                   bf16* __restrict__ z) {
  const int S = 1024, E = 64;
  __shared__ __align__(16) bf16 Klds[64 * 64];
  __shared__ __align__(16) bf16 Vlds[64 * 64];
  __shared__ __align__(16) bf16 Plds[4 * 16 * 64];
  const int pb = blockIdx.x;   // 0..7
  const int bh = blockIdx.y;   // 0..95
  const int t = threadIdx.x;
  const int wave = t >> 6, lane = t & 63;
  const int lm = lane & 15, quad = lane >> 4;
  const size_t bh_se = (size_t)bh * S * E;
  const int b = bh / 12, h = bh - b * 12;

  for (int seg = 0; seg < 2; seg++) {
    const int qt = seg ? (15 - pb) : pb;
    const int qrow = qt * 64 + wave * 16 + lm;
    bf16x8 qf0 = *(const bf16x8*)(q + bh_se + (size_t)qrow * E + quad * 8);
    bf16x8 qf1 = *(const bf16x8*)(q + bh_se + (size_t)qrow * E + 32 + quad * 8);

    f32x4 acco[4] = {};
    float lsum[4] = {0.f, 0.f, 0.f, 0.f};

    for (int kt = 0; kt <= qt; kt++) {
#pragma unroll
      for (int i = 0; i < 2; i++) {
        int c = i * 256 + t;
        int r = c >> 3, cs = c & 7;
        int sw = (cs ^ (r & 7)) << 3;
        async16(k + bh_se + (size_t)(kt * 64 + r) * E + sw, &Klds[c * 8]);
        async16(vt + bh_se + (size_t)r * S + kt * 64 + sw, &Vlds[c * 8]);
      }
      __syncthreads();

      f32x4 accs[4] = {};
#pragma unroll
      for (int ni = 0; ni < 4; ni++) {
        int row = ni * 16 + lm;
        bf16x8 kf0 = *(const bf16x8*)&Klds[row * 64 + ((quad ^ (lm & 7)) << 3)];
        bf16x8 kf1 = *(const bf16x8*)&Klds[row * 64 + (((4 + quad) ^ (lm & 7)) << 3)];
        accs[ni] = mfma16(qf0, kf0, accs[ni]);
        accs[ni] = mfma16(qf1, kf1, accs[ni]);
      }

      float pv[4][4];
      const int qg = wave * 16 + quad * 4;
      if (kt == qt) {
#pragma unroll
        for (int ni = 0; ni < 4; ni++)
#pragma unroll
          for (int reg = 0; reg < 4; reg++) {
            float e_ = __expf(accs[ni][reg]);
            pv[ni][reg] = ((ni * 16 + lm) > (qg + reg)) ? 0.f : e_;
          }
      } else {
#pragma unroll
        for (int ni = 0; ni < 4; ni++)
#pragma unroll
          for (int reg = 0; reg < 4; reg++)
            pv[ni][reg] = __expf(accs[ni][reg]);
      }

#pragma unroll
      for (int ni = 0; ni < 4; ni++)
#pragma unroll
        for (int reg = 0; reg < 4; reg++) {
          lsum[reg] += pv[ni][reg];
          int pr = quad * 4 + reg;
          int ce = ni * 16 + lm;
          Plds[wave * 1024 + pr * 64 + (((ce >> 3) ^ (pr & 7)) << 3) + (ce & 7)] =
              f2bf(pv[ni][reg]);
        }
      __syncthreads();

      bf16x8 pf0 = *(const bf16x8*)&Plds[wave * 1024 + lm * 64 + ((quad ^ (lm & 7)) << 3)];
      bf16x8 pf1 = *(const bf16x8*)&Plds[wave * 1024 + lm * 64 + (((4 + quad) ^ (lm & 7)) << 3)];
#pragma unroll
      for (int ni = 0; ni < 4; ni++) {
        int row = ni * 16 + lm;
        bf16x8 vf0 = *(const bf16x8*)&Vlds[row * 64 + ((quad ^ (lm & 7)) << 3)];
        bf16x8 vf1 = *(const bf16x8*)&Vlds[row * 64 + (((4 + quad) ^ (lm & 7)) << 3)];
        acco[ni] = mfma16(pf0, vf0, acco[ni]);
        acco[ni] = mfma16(pf1, vf1, acco[ni]);
      }
      __syncthreads();
    }

#pragma unroll
    for (int reg = 0; reg < 4; reg++) {
#pragma unroll
      for (int off = 1; off < 16; off <<= 1) lsum[reg] += __shfl_xor(lsum[reg], off, 16);
    }
    float rl[4];
#pragma unroll
    for (int reg = 0; reg < 4; reg++) rl[reg] = 1.0f / lsum[reg];

#pragma unroll
    for (int ni = 0; ni < 4; ni++)
#pragma unroll
      for (int reg = 0; reg < 4; reg++) {
        int srow = qt * 64 + wave * 16 + quad * 4 + reg;
        size_t idx = (((size_t)(b * 1024 + srow) * 12 + h) << 6) + ni * 16 + lm;
        z[idx] = f2bf(acco[ni][reg] * rl[reg]);
      }
  }
}

// ---------------- launch ----------------
extern "C" void kernel_launch(void* const* d_in, const int* in_sizes, int n_in,
                              void* d_out, int out_size, void* d_ws, size_t ws_size,
                              hipStream_t stream) {
  (void)in_sizes; (void)n_in; (void)out_size; (void)ws_size;
  const float* resid_pre = (const float*)d_in[0];
  const float* ln1_w = (const float*)d_in[1];
  const float* ln1_b = (const float*)d_in[2];
  const float* W_Q = (const float*)d_in[3];
  const float* b_Q = (const float*)d_in[4];
  const float* W_K = (const float*)d_in[5];
  const float* b_K = (const float*)d_in[6];
  const float* W_V = (const float*)d_in[7];
  const float* b_V = (const float*)d_in[8];
  const float* W_O = (const float*)d_in[9];
  const float* b_O = (const float*)d_in[10];
  const float* ln2_w = (const float*)d_in[11];
  const float* ln2_b = (const float*)d_in[12];
  const float* W_in = (const float*)d_in[13];
  const float* b_in = (const float*)d_in[14];
  const float* W_out = (const float*)d_in[15];
  const float* b_out = (const float*)d_in[16];

  char* ws = (char*)d_ws;
  const size_t EB = (size_t)8192 * 768;
  bf16* n1     = (bf16*)(ws);
  bf16* qb     = (bf16*)(ws + EB * 2);   // q, k, vt contiguous (EB elements each)
  bf16* zb     = (bf16*)(ws + EB * 8);
  float* resid = (float*)(ws + EB * 10);
  bf16* act    = (bf16*)(ws + EB * 2);   // reuse q..z region post-attention
  char* wsw = ws + EB * 14;
  bf16* Wqkv_t = (bf16*)(wsw);           // [2304,768]: Wq_t | Wk_t | Wv_t
  bf16* Wo_t   = (bf16*)(wsw + 3 * 1179648);
  bf16* Win_t  = (bf16*)(wsw + 4 * 1179648);
  bf16* Wout_t = (bf16*)(wsw + 4 * 1179648 + 4718592);
  float* bias_qkv = (float*)(wsw + 4 * 1179648 + 4718592 + 9437184);
  bf16* kb  = qb + EB;
  bf16* vtb = qb + 2 * EB;

  // merged: LN1 + QKV gathers + W_O/W_in/W_out transposes + bias pack
  prep_all<<<15113, 256, 0, stream>>>(resid_pre, ln1_w, ln1_b, n1,
                                      W_Q, W_K, W_V, Wqkv_t,
                                      W_O, Wo_t, W_in, Win_t, W_out, Wout_t,
                                      b_Q, b_K, b_V, bias_qkv);

  gemm_bt512<MODE_QKV><<<dim3(32, 18), 512, 0, stream>>>(
      n1, Wqkv_t, bias_qkv, qb, 8192, 2304, 768);

  attn_kernel<<<dim3(8, 96), 256, 0, stream>>>(qb, kb, vtb, zb);

  gemm_bt<MODE_ADDF, 64><<<dim3(128, 6), 256, 0, stream>>>(
      zb, Wo_t, b_O, resid_pre, resid, nullptr, 8192, 768, 768);

  ln_kernel<<<8192, 256, 0, stream>>>(resid, ln2_w, ln2_b, n1);

  gemm_bt512<MODE_GELU><<<dim3(32, 24), 512, 0, stream>>>(
      n1, Win_t, b_in, act, 8192, 3072, 768);

  gemm_bt<MODE_ADDF, 64><<<dim3(128, 6), 256, 0, stream>>>(
      act, Wout_t, b_out, resid, (float*)d_out, nullptr, 8192, 768, 3072);
}

// Round 5
// 342.502 us; speedup vs baseline: 1.1269x; 1.0080x over previous
//
#include <hip/hip_runtime.h>
#include <hip/hip_bf16.h>
#include <stdint.h>
#include <math.h>

typedef __bf16 bf16x8 __attribute__((ext_vector_type(8)));
typedef float f32x4 __attribute__((ext_vector_type(4)));
using bf16 = __hip_bfloat16;

__device__ inline float bf2f(bf16 x) { return __bfloat162float(x); }
__device__ inline bf16 f2bf(float x) { return __float2bfloat16(x); }

__device__ inline f32x4 mfma16(bf16x8 a, bf16x8 b, f32x4 c) {
  return __builtin_amdgcn_mfma_f32_16x16x32_bf16(a, b, c, 0, 0, 0);
}

// async global->LDS, 16B per lane. LDS dest must be wave-uniform base + lane*16.
__device__ inline void async16(const bf16* g, bf16* l) {
  __builtin_amdgcn_global_load_lds(
      (const __attribute__((address_space(1))) unsigned int*)g,
      (__attribute__((address_space(3))) unsigned int*)l, 16, 0, 0);
}

// fast GPT-2 gelu: tanh(u) = 1 - 2/(exp(2u)+1); exact limits at +-inf
__device__ inline float gelu_new(float x) {
  float u2 = 1.5957691216057308f * (x + 0.044715f * x * x * x);
  float e = __expf(u2);
  float t = 1.0f - 2.0f * __builtin_amdgcn_rcpf(e + 1.0f);
  return 0.5f * x * (1.0f + t);
}

// ---------------- LayerNorm body (used by prep_all and ln_kernel) ----------------
__device__ inline void ln_body(const float* __restrict__ x, const float* __restrict__ w,
                               const float* __restrict__ bb, bf16* __restrict__ out,
                               int row, int t, float* red) {
  size_t base = (size_t)row * 768;
  float v0 = x[base + t];
  float v1 = x[base + t + 256];
  float v2 = x[base + t + 512];
  float s = v0 + v1 + v2;
  float ss = v0 * v0 + v1 * v1 + v2 * v2;
#pragma unroll
  for (int off = 32; off > 0; off >>= 1) {
    s += __shfl_down(s, off, 64);
    ss += __shfl_down(ss, off, 64);
  }
  int wv = t >> 6, ln = t & 63;
  if (ln == 0) { red[wv] = s; red[4 + wv] = ss; }
  __syncthreads();
  s = red[0] + red[1] + red[2] + red[3];
  ss = red[4] + red[5] + red[6] + red[7];
  float mu = s * (1.0f / 768.0f);
  float var = ss * (1.0f / 768.0f) - mu * mu;
  float rinv = rsqrtf(var + 1e-5f);
  out[base + t]       = f2bf((v0 - mu) * rinv * w[t]       + bb[t]);
  out[base + t + 256] = f2bf((v1 - mu) * rinv * w[t + 256] + bb[t + 256]);
  out[base + t + 512] = f2bf((v2 - mu) * rinv * w[t + 512] + bb[t + 512]);
}

__global__ __launch_bounds__(256) void ln_kernel(const float* __restrict__ x,
                                                 const float* __restrict__ w,
                                                 const float* __restrict__ bb,
                                                 bf16* __restrict__ out) {
  __shared__ float red[8];
  ln_body(x, w, bb, out, blockIdx.x, threadIdx.x, red);
}

// ---------------- transpose body: fp32 in[R][C] -> bf16 out[C][R], 32x32 tile ----------------
__device__ inline void transpose_body(const float* __restrict__ in, bf16* __restrict__ out,
                                      int R, int C, int bx, int by, int t,
                                      float (*tile)[33]) {
  int tx = t & 31, ty = t >> 5;
  int r0 = bx * 32, c0 = by * 32;
#pragma unroll
  for (int j = 0; j < 32; j += 8)
    tile[ty + j][tx] = in[(size_t)(r0 + ty + j) * C + c0 + tx];
  __syncthreads();
#pragma unroll
  for (int j = 0; j < 32; j += 8)
    out[(size_t)(c0 + ty + j) * R + r0 + tx] = f2bf(tile[tx][ty + j]);
}

// ---------------- merged prep: LN1 + all weight transposes + bias pack ----------------
__global__ __launch_bounds__(256) void prep_all(
    const float* __restrict__ resid_pre, const float* __restrict__ ln1_w,
    const float* __restrict__ ln1_b, bf16* __restrict__ n1,
    const float* __restrict__ Wq, const float* __restrict__ Wk,
    const float* __restrict__ Wv, bf16* __restrict__ Wqkv_t,
    const float* __restrict__ W_O, bf16* __restrict__ Wo_t,
    const float* __restrict__ W_in, bf16* __restrict__ Win_t,
    const float* __restrict__ W_out, bf16* __restrict__ Wout_t,
    const float* __restrict__ bq, const float* __restrict__ bk,
    const float* __restrict__ bv, float* __restrict__ bias_qkv) {
  __shared__ float tile[32][33];
  const int t = threadIdx.x;
  int bid = blockIdx.x;
  if (bid < 8192) {                      // LN1
    ln_body(resid_pre, ln1_w, ln1_b, n1, bid, t, &tile[0][0]);
    return;
  }
  bid -= 8192;
  if (bid < 1728) {                      // QKV gather: per-head 768x64 -> 64x768
    int z = bid / 48, r = bid - z * 48;
    int which = z / 12, h = z - which * 12;
    const float* W = (which == 0) ? Wq : ((which == 1) ? Wk : Wv);
    transpose_body(W + (size_t)h * 768 * 64,
                   Wqkv_t + (size_t)which * 589824 + (size_t)h * 64 * 768,
                   768, 64, r % 24, r / 24, t, tile);
    return;
  }
  bid -= 1728;
  if (bid < 576) {                       // W_O [768,768] -> [768,768]^T
    transpose_body(W_O, Wo_t, 768, 768, bid % 24, bid / 24, t, tile);
    return;
  }
  bid -= 576;
  if (bid < 2304) {                      // W_in [768,3072] -> [3072,768]
    transpose_body(W_in, Win_t, 768, 3072, bid % 24, bid / 24, t, tile);
    return;
  }
  bid -= 2304;
  if (bid < 2304) {                      // W_out [3072,768] -> [768,3072]
    transpose_body(W_out, Wout_t, 3072, 768, bid % 96, bid / 96, t, tile);
    return;
  }
  bid -= 2304;
  int i = bid * 256 + t;                 // bias pack, 9 blocks
  if (i < 2304)
    bias_qkv[i] = (i < 768) ? bq[i] : ((i < 1536) ? bk[i - 768] : bv[i - 1536]);
}

// ---------------- GEMM: C[M,N] = A[M,K] * BT[N,K]^T (16x16x32, xor-swizzled LDS) ----
// 1-D grid with XCD-aware bijective swizzle (requires gridDim.x % 8 == 0).
// Logical tile l = (bid%8)*(nwg/8) + bid/8; by = l % gy (fastest) so each XCD's
// chunk covers ALL N-panels for a few A-row-panels -> per-XCD L2 working set is
// {few A panels + full B}, instead of random cross-XCD re-fetch.
enum { MODE_QKV = 0, MODE_ADDF = 2, MODE_GELU = 3 };

template <int MODE, int MROWS>
__global__ __launch_bounds__(256) void gemm_bt(
    const bf16* __restrict__ A, const bf16* __restrict__ BT,
    const float* __restrict__ bias,
    const float* __restrict__ addend,
    float* __restrict__ out_f32,
    bf16* __restrict__ out_bf16,
    int M, int N, int K, int gy) {
  constexpr int MI = MROWS / 32;
  __shared__ __align__(16) bf16 smem[(MROWS + 128) * 64];
  bf16* Alds = smem;
  bf16* Blds = smem + MROWS * 64;
  const int t = threadIdx.x;
  const int wave = t >> 6, lane = t & 63;
  const int lm = lane & 15, quad = lane >> 4;
  const int wm = wave >> 1, wn = wave & 1;

  const int cpx = gridDim.x >> 3;
  const int l = (blockIdx.x & 7) * cpx + (blockIdx.x >> 3);
  const int by = l % gy, bx = l / gy;
  const int m0 = bx * MROWS, n0 = by * 128;

  f32x4 acc[MI][4] = {};

  for (int k0 = 0; k0 < K; k0 += 64) {
#pragma unroll
    for (int i = 0; i < MI; i++) {
      int c = i * 256 + t;
      int r = c >> 3, cs = c & 7;
      async16(A + (size_t)(m0 + r) * K + k0 + ((cs ^ (r & 7)) << 3), &Alds[c * 8]);
    }
#pragma unroll
    for (int i = 0; i < 4; i++) {
      int c = i * 256 + t;
      int r = c >> 3, cs = c & 7;
      async16(BT + (size_t)(n0 + r) * K + k0 + ((cs ^ (r & 7)) << 3), &Blds[c * 8]);
    }
    __syncthreads();
#pragma unroll
    for (int kk = 0; kk < 64; kk += 32) {
      const int cbase = kk >> 3;  // 0 or 4
      bf16x8 af[MI], bfr[4];
#pragma unroll
      for (int mi = 0; mi < MI; mi++)
        af[mi] = *(const bf16x8*)&Alds[(wm * (MROWS / 2) + mi * 16 + lm) * 64 +
                                       (((cbase + quad) ^ (lm & 7)) << 3)];
#pragma unroll
      for (int ni = 0; ni < 4; ni++)
        bfr[ni] = *(const bf16x8*)&Blds[(wn * 64 + ni * 16 + lm) * 64 +
                                        (((cbase + quad) ^ (lm & 7)) << 3)];
#pragma unroll
      for (int mi = 0; mi < MI; mi++)
#pragma unroll
        for (int ni = 0; ni < 4; ni++)
          acc[mi][ni] = mfma16(af[mi], bfr[ni], acc[mi][ni]);
    }
    __syncthreads();
  }

  // ---------------- epilogue: per-wave LDS transpose -> coalesced 16B stores ----------------
  float bv[4];
#pragma unroll
  for (int ni = 0; ni < 4; ni++) bv[ni] = bias[n0 + wn * 64 + ni * 16 + lm];

  float* sc = (float*)smem + wave * 1088;  // 16x67 (row-major) or 64x17 (V-transposed)
  const bool vseg = (MODE == MODE_QKV) && ((n0 + wn * 64) >= 1536);

#pragma unroll
  for (int mi = 0; mi < MI; mi++) {
    __syncthreads();  // WAR: previous reads done before overwriting scratch
#pragma unroll
    for (int ni = 0; ni < 4; ni++)
#pragma unroll
      for (int reg = 0; reg < 4; reg++) {
        float val = acc[mi][ni][reg] + bv[ni];
        if (vseg) sc[(ni * 16 + lm) * 17 + quad * 4 + reg] = val;
        else      sc[(quad * 4 + reg) * 67 + ni * 16 + lm] = val;
      }
    __syncthreads();  // RAW: scratch writes visible before cross-lane reads

    if (!vseg) {
#pragma unroll
      for (int p = 0; p < 2; p++) {
        int rl = p * 8 + (lane >> 3);
        int cl = (lane & 7) * 8;
        float v[8];
#pragma unroll
        for (int j = 0; j < 8; j++) v[j] = sc[rl * 67 + cl + j];
        int rm = m0 + wm * (MROWS / 2) + mi * 16 + rl;
        int cn0 = n0 + wn * 64 + cl;
        if constexpr (MODE == MODE_GELU) {
          bf16x8 o;
#pragma unroll
          for (int j = 0; j < 8; j++) o[j] = (__bf16)gelu_new(v[j]);
          *(bf16x8*)(out_bf16 + (size_t)rm * N + cn0) = o;
        } else if constexpr (MODE == MODE_ADDF) {
          size_t idx = (size_t)rm * N + cn0;
          f32x4 a0 = *(const f32x4*)(addend + idx);
          f32x4 a1 = *(const f32x4*)(addend + idx + 4);
          f32x4 o0, o1;
#pragma unroll
          for (int j = 0; j < 4; j++) { o0[j] = v[j] + a0[j]; o1[j] = v[4 + j] + a1[j]; }
          *(f32x4*)(out_f32 + idx) = o0;
          *(f32x4*)(out_f32 + idx + 4) = o1;
        } else {  // MODE_QKV, seg 0/1 (Q,K): [b,h,s,e]; Q pre-scaled by 1/sqrt(d)
          int seg = cn0 / 768;
          int lnn = cn0 - seg * 768;
          int h2 = lnn >> 6, e0 = lnn & 63;
          int b2 = rm >> 10, sq = rm & 1023;
          float scale = (seg == 0) ? 0.125f : 1.0f;
          bf16x8 o;
#pragma unroll
          for (int j = 0; j < 8; j++) o[j] = (__bf16)(v[j] * scale);
          *(bf16x8*)(out_bf16 + (size_t)seg * 6291456 +
                     (((size_t)(b2 * 12 + h2) * 1024 + sq) << 6) + e0) = o;
        }
      }
    } else {
      // V chunk: scratch is [e_local 64][s_local 16]; store [b,h,e,s] runs along s
#pragma unroll
      for (int p = 0; p < 2; p++) {
        float v[8];
#pragma unroll
        for (int j = 0; j < 8; j++) v[j] = sc[lane * 17 + p * 8 + j];
        int e_he = n0 + wn * 64 + lane;
        int lnn = e_he - 1536;
        int h2 = lnn >> 6, e2 = lnn & 63;
        int s0 = m0 + wm * (MROWS / 2) + mi * 16 + p * 8;
        int b2 = s0 >> 10, sq = s0 & 1023;
        bf16x8 o;
#pragma unroll
        for (int j = 0; j < 8; j++) o[j] = (__bf16)v[j];
        *(bf16x8*)(out_bf16 + (size_t)2 * 6291456 +
                   (((size_t)(b2 * 12 + h2) * 64 + e2) << 10) + sq) = o;
      }
    }
  }
}

// ---------------- flash attention (swizzled K/V/P tiles; Q pre-scaled) ----------------
// 1-D grid of 768 blocks, XCD-clustered: all 8 pb-blocks of one (b,h) land on the
// same XCD so that head's 256KB K/V is fetched into one L2 once (was 8 L2s).
__global__ __launch_bounds__(256) void attn_kernel(const bf16* __restrict__ q,
                                                   const bf16* __restrict__ k,
                                                   const bf16* __restrict__ vt,
                                                   bf16* __restrict__ z) {
  const int S = 1024, E = 64;
  __shared__ __align__(16) bf16 Klds[64 * 64];
  __shared__ __align__(16) bf16 Vlds[64 * 64];
  __shared__ __align__(16) bf16 Plds[4 * 16 * 64];
  const int l = (blockIdx.x & 7) * 96 + (blockIdx.x >> 3);
  const int pb = l & 7;    // 0..7
  const int bh = l >> 3;   // 0..95
  const int t = threadIdx.x;
  const int wave = t >> 6, lane = t & 63;
  const int lm = lane & 15, quad = lane >> 4;
  const size_t bh_se = (size_t)bh * S * E;
  const int b = bh / 12, h = bh - b * 12;

  for (int seg = 0; seg < 2; seg++) {
    const int qt = seg ? (15 - pb) : pb;
    const int qrow = qt * 64 + wave * 16 + lm;
    bf16x8 qf0 = *(const bf16x8*)(q + bh_se + (size_t)qrow * E + quad * 8);
    bf16x8 qf1 = *(const bf16x8*)(q + bh_se + (size_t)qrow * E + 32 + quad * 8);

    f32x4 acco[4] = {};
    float lsum[4] = {0.f, 0.f, 0.f, 0.f};

    for (int kt = 0; kt <= qt; kt++) {
#pragma unroll
      for (int i = 0; i < 2; i++) {
        int c = i * 256 + t;
        int r = c >> 3, cs = c & 7;
        int sw = (cs ^ (r & 7)) << 3;
        async16(k + bh_se + (size_t)(kt * 64 + r) * E + sw, &Klds[c * 8]);
        async16(vt + bh_se + (size_t)r * S + kt * 64 + sw, &Vlds[c * 8]);
      }
      __syncthreads();

      f32x4 accs[4] = {};
#pragma unroll
      for (int ni = 0; ni < 4; ni++) {
        int row = ni * 16 + lm;
        bf16x8 kf0 = *(const bf16x8*)&Klds[row * 64 + ((quad ^ (lm & 7)) << 3)];
        bf16x8 kf1 = *(const bf16x8*)&Klds[row * 64 + (((4 + quad) ^ (lm & 7)) << 3)];
        accs[ni] = mfma16(qf0, kf0, accs[ni]);
        accs[ni] = mfma16(qf1, kf1, accs[ni]);
      }

      float pv[4][4];
      const int qg = wave * 16 + quad * 4;
      if (kt == qt) {
#pragma unroll
        for (int ni = 0; ni < 4; ni++)
#pragma unroll
          for (int reg = 0; reg < 4; reg++) {
            float e_ = __expf(accs[ni][reg]);
            pv[ni][reg] = ((ni * 16 + lm) > (qg + reg)) ? 0.f : e_;
          }
      } else {
#pragma unroll
        for (int ni = 0; ni < 4; ni++)
#pragma unroll
          for (int reg = 0; reg < 4; reg++)
            pv[ni][reg] = __expf(accs[ni][reg]);
      }

#pragma unroll
      for (int ni = 0; ni < 4; ni++)
#pragma unroll
        for (int reg = 0; reg < 4; reg++) {
          lsum[reg] += pv[ni][reg];
          int pr = quad * 4 + reg;
          int ce = ni * 16 + lm;
          Plds[wave * 1024 + pr * 64 + (((ce >> 3) ^ (pr & 7)) << 3) + (ce & 7)] =
              f2bf(pv[ni][reg]);
        }
      __syncthreads();

      bf16x8 pf0 = *(const bf16x8*)&Plds[wave * 1024 + lm * 64 + ((quad ^ (lm & 7)) << 3)];
      bf16x8 pf1 = *(const bf16x8*)&Plds[wave * 1024 + lm * 64 + (((4 + quad) ^ (lm & 7)) << 3)];
#pragma unroll
      for (int ni = 0; ni < 4; ni++) {
        int row = ni * 16 + lm;
        bf16x8 vf0 = *(const bf16x8*)&Vlds[row * 64 + ((quad ^ (lm & 7)) << 3)];
        bf16x8 vf1 = *(const bf16x8*)&Vlds[row * 64 + (((4 + quad) ^ (lm & 7)) << 3)];
        acco[ni] = mfma16(pf0, vf0, acco[ni]);
        acco[ni] = mfma16(pf1, vf1, acco[ni]);
      }
      __syncthreads();
    }

#pragma unroll
    for (int reg = 0; reg < 4; reg++) {
#pragma unroll
      for (int off = 1; off < 16; off <<= 1) lsum[reg] += __shfl_xor(lsum[reg], off, 16);
    }
    float rl[4];
#pragma unroll
    for (int reg = 0; reg < 4; reg++) rl[reg] = 1.0f / lsum[reg];

#pragma unroll
    for (int ni = 0; ni < 4; ni++)
#pragma unroll
      for (int reg = 0; reg < 4; reg++) {
        int srow = qt * 64 + wave * 16 + quad * 4 + reg;
        size_t idx = (((size_t)(b * 1024 + srow) * 12 + h) << 6) + ni * 16 + lm;
        z[idx] = f2bf(acco[ni][reg] * rl[reg]);
      }
  }
}

// ---------------- launch ----------------
extern "C" void kernel_launch(void* const* d_in, const int* in_sizes, int n_in,
                              void* d_out, int out_size, void* d_ws, size_t ws_size,
                              hipStream_t stream) {
  (void)in_sizes; (void)n_in; (void)out_size; (void)ws_size;
  const float* resid_pre = (const float*)d_in[0];
  const float* ln1_w = (const float*)d_in[1];
  const float* ln1_b = (const float*)d_in[2];
  const float* W_Q = (const float*)d_in[3];
  const float* b_Q = (const float*)d_in[4];
  const float* W_K = (const float*)d_in[5];
  const float* b_K = (const float*)d_in[6];
  const float* W_V = (const float*)d_in[7];
  const float* b_V = (const float*)d_in[8];
  const float* W_O = (const float*)d_in[9];
  const float* b_O = (const float*)d_in[10];
  const float* ln2_w = (const float*)d_in[11];
  const float* ln2_b = (const float*)d_in[12];
  const float* W_in = (const float*)d_in[13];
  const float* b_in = (const float*)d_in[14];
  const float* W_out = (const float*)d_in[15];
  const float* b_out = (const float*)d_in[16];

  char* ws = (char*)d_ws;
  const size_t EB = (size_t)8192 * 768;
  bf16* n1     = (bf16*)(ws);
  bf16* qb     = (bf16*)(ws + EB * 2);   // q, k, vt contiguous (EB elements each)
  bf16* zb     = (bf16*)(ws + EB * 8);
  float* resid = (float*)(ws + EB * 10);
  bf16* act    = (bf16*)(ws + EB * 2);   // reuse q..z region post-attention
  char* wsw = ws + EB * 14;
  bf16* Wqkv_t = (bf16*)(wsw);           // [2304,768]: Wq_t | Wk_t | Wv_t
  bf16* Wo_t   = (bf16*)(wsw + 3 * 1179648);
  bf16* Win_t  = (bf16*)(wsw + 4 * 1179648);
  bf16* Wout_t = (bf16*)(wsw + 4 * 1179648 + 4718592);
  float* bias_qkv = (float*)(wsw + 4 * 1179648 + 4718592 + 9437184);
  bf16* kb  = qb + EB;
  bf16* vtb = qb + 2 * EB;

  // merged: LN1 + QKV gathers + W_O/W_in/W_out transposes + bias pack
  prep_all<<<15113, 256, 0, stream>>>(resid_pre, ln1_w, ln1_b, n1,
                                      W_Q, W_K, W_V, Wqkv_t,
                                      W_O, Wo_t, W_in, Win_t, W_out, Wout_t,
                                      b_Q, b_K, b_V, bias_qkv);

  // QKV: 64 x 18 tiles -> 1152 blocks (%8==0), by-fastest XCD clustering
  gemm_bt<MODE_QKV, 128><<<1152, 256, 0, stream>>>(
      n1, Wqkv_t, bias_qkv, nullptr, nullptr, qb, 8192, 2304, 768, 18);

  attn_kernel<<<768, 256, 0, stream>>>(qb, kb, vtb, zb);

  // W_O proj + residual add: 128 x 6 tiles -> 768 blocks
  gemm_bt<MODE_ADDF, 64><<<768, 256, 0, stream>>>(
      zb, Wo_t, b_O, resid_pre, resid, nullptr, 8192, 768, 768, 6);

  ln_kernel<<<8192, 256, 0, stream>>>(resid, ln2_w, ln2_b, n1);

  // MLP-in + gelu: 64 x 24 tiles -> 1536 blocks
  gemm_bt<MODE_GELU, 128><<<1536, 256, 0, stream>>>(
      n1, Win_t, b_in, nullptr, nullptr, act, 8192, 3072, 768, 24);

  // MLP-out + residual add: 128 x 6 tiles -> 768 blocks
  gemm_bt<MODE_ADDF, 64><<<768, 256, 0, stream>>>(
      act, Wout_t, b_out, resid, (float*)d_out, nullptr, 8192, 768, 3072, 6);
}